// Round 1
// baseline (762.956 us; speedup 1.0000x reference)
//
#include <hip/hip_runtime.h>
#include <math.h>

// ---------------- degree / norm precompute ----------------

__global__ void k_init_deg(float* __restrict__ deg, int N) {
    int i = blockIdx.x * blockDim.x + threadIdx.x;
    if (i < N) deg[i] = 1.0f;  // self-loop weight
}

__global__ void k_deg_acc(const int* __restrict__ dst, const float* __restrict__ ew,
                          float* __restrict__ deg, int E) {
    int e = blockIdx.x * blockDim.x + threadIdx.x;
    if (e < E) atomicAdd(&deg[dst[e]], ew[e]);
}

__global__ void k_dinv(float* __restrict__ deg, int N) {
    int i = blockIdx.x * blockDim.x + threadIdx.x;
    if (i < N) deg[i] = rsqrtf(deg[i]);  // deg >= 1 guaranteed (self-loop)
}

__global__ void k_norm(const int* __restrict__ src, const int* __restrict__ dst,
                       const float* __restrict__ ew, const float* __restrict__ dinv,
                       float* __restrict__ norm, int E) {
    int e = blockIdx.x * blockDim.x + threadIdx.x;
    if (e < E) norm[e] = dinv[src[e]] * ew[e] * dinv[dst[e]];
}

// ---------------- aggregation: agg = \hat{A} h  (done BEFORE matmul) ----------------

// self-loop term: agg[n][f] = h[n][f] * dinv[n]^2  (also serves as zero-init)
__global__ void k_self(const float* __restrict__ h, const float* __restrict__ dinv,
                       float* __restrict__ agg, int total, int shiftF) {
    int i = blockIdx.x * blockDim.x + threadIdx.x;
    if (i < total) {
        int n = i >> shiftF;
        float dv = dinv[n];
        agg[i] = h[i] * dv * dv;
    }
}

// edge term: agg[dst][f] += h[src][f] * norm[e]
__global__ void k_edge(const int* __restrict__ src, const int* __restrict__ dst,
                       const float* __restrict__ norm, const float* __restrict__ h,
                       float* __restrict__ agg, long long total, int shiftF, int maskF) {
    long long gid = (long long)blockIdx.x * blockDim.x + threadIdx.x;
    if (gid >= total) return;
    int e = (int)(gid >> shiftF);
    int f = (int)(gid & maskF);
    int s = src[e], d = dst[e];
    float v = h[(long long)s << shiftF | f] * norm[e];
    atomicAdd(&agg[(long long)d << shiftF | f], v);
}

// ---------------- fp32 tiled GEMM: C = relu(A @ W + bias) ----------------
// A: [M,K] row-major, W: [K,Fout] row-major. BM=BN=128, 256 threads, 8x8/thread
// (split 4+4 layout for conflict-free b128 LDS reads).

template <int BK>
__global__ __launch_bounds__(256) void k_gemm_bias_relu(
    const float* __restrict__ A, const float* __restrict__ W,
    const float* __restrict__ bias, float* __restrict__ C,
    int M, int K, int Fout) {
    const int BM = 128, BN = 128;
    __shared__ float As[BK][BM + 4];  // +4: rows stay 16B-aligned, 2-way bank alias (free)
    __shared__ float Bs[BK][BN];

    int bm = blockIdx.x * BM;
    int bn = blockIdx.y * BN;
    int tid = threadIdx.x;
    int tx = tid & 15;
    int ty = tid >> 4;

    float acc[8][8];
#pragma unroll
    for (int i = 0; i < 8; ++i)
#pragma unroll
        for (int j = 0; j < 8; ++j) acc[i][j] = 0.f;

    for (int k0 = 0; k0 < K; k0 += BK) {
        // A tile (transposed into LDS): k fastest for partial global coalescing
#pragma unroll
        for (int i = tid; i < BM * BK; i += 256) {
            int k = i % BK;
            int m = i / BK;
            int gm = bm + m;
            As[k][m] = (gm < M) ? A[(long long)gm * K + k0 + k] : 0.f;
        }
        // W tile: n fastest -> fully coalesced
#pragma unroll
        for (int i = tid; i < BK * BN; i += 256) {
            int n = i % BN;
            int k = i / BN;
            Bs[k][n] = W[(long long)(k0 + k) * Fout + bn + n];
        }
        __syncthreads();

#pragma unroll
        for (int k = 0; k < BK; ++k) {
            float a[8], b[8];
            float4 a0 = *(const float4*)&As[k][ty * 4];
            float4 a1 = *(const float4*)&As[k][ty * 4 + 64];
            float4 b0 = *(const float4*)&Bs[k][tx * 4];
            float4 b1 = *(const float4*)&Bs[k][tx * 4 + 64];
            a[0] = a0.x; a[1] = a0.y; a[2] = a0.z; a[3] = a0.w;
            a[4] = a1.x; a[5] = a1.y; a[6] = a1.z; a[7] = a1.w;
            b[0] = b0.x; b[1] = b0.y; b[2] = b0.z; b[3] = b0.w;
            b[4] = b1.x; b[5] = b1.y; b[6] = b1.z; b[7] = b1.w;
#pragma unroll
            for (int i = 0; i < 8; ++i)
#pragma unroll
                for (int j = 0; j < 8; ++j) acc[i][j] += a[i] * b[j];
        }
        __syncthreads();
    }

    // epilogue: + bias, relu, vectorized store
    float4 bi0 = *(const float4*)&bias[bn + tx * 4];
    float4 bi1 = *(const float4*)&bias[bn + tx * 4 + 64];
    float bb[8] = {bi0.x, bi0.y, bi0.z, bi0.w, bi1.x, bi1.y, bi1.z, bi1.w};
#pragma unroll
    for (int i = 0; i < 8; ++i) {
        int gm = bm + ((i < 4) ? (ty * 4 + i) : (64 + ty * 4 + i - 4));
        if (gm >= M) continue;
        float4 v0, v1;
        float* v0p = &v0.x;
        float* v1p = &v1.x;
#pragma unroll
        for (int j = 0; j < 4; ++j) {
            float x0 = acc[i][j] + bb[j];
            float x1 = acc[i][j + 4] + bb[j + 4];
            v0p[j] = fmaxf(x0, 0.f);
            v1p[j] = fmaxf(x1, 0.f);
        }
        *(float4*)&C[(long long)gm * Fout + bn + tx * 4] = v0;
        *(float4*)&C[(long long)gm * Fout + bn + tx * 4 + 64] = v1;
    }
}

// ---------------- fused mean-pool + FC + sigmoid ----------------
// batch is sorted ascending; block g binary-searches its node range.
// Requires F == 512 and blockDim == 256.

__global__ __launch_bounds__(256) void k_pool_fc(
    const float* __restrict__ h3, const int* __restrict__ batch,
    const float* __restrict__ Wfc, const float* __restrict__ bfc,
    float* __restrict__ out, int N) {
    int g = blockIdx.x;
    int t = threadIdx.x;

    // lower_bound(batch, g) and lower_bound(batch, g+1)
    int lo = 0, hi = N;
    while (lo < hi) { int mid = (lo + hi) >> 1; if (batch[mid] < g) lo = mid + 1; else hi = mid; }
    int start = lo;
    hi = N;
    while (lo < hi) { int mid = (lo + hi) >> 1; if (batch[mid] < g + 1) lo = mid + 1; else hi = mid; }
    int end = lo;

    float acc0 = 0.f, acc1 = 0.f;
    for (int n = start; n < end; ++n) {
        acc0 += h3[(long long)n * 512 + t];
        acc1 += h3[(long long)n * 512 + t + 256];
    }
    float partial = acc0 * Wfc[t] + acc1 * Wfc[t + 256];

    __shared__ float red[256];
    red[t] = partial;
    __syncthreads();
    for (int s = 128; s > 0; s >>= 1) {
        if (t < s) red[t] += red[t + s];
        __syncthreads();
    }
    if (t == 0) {
        float cnt = (float)(end - start);
        if (cnt < 1.f) cnt = 1.f;
        float z = red[0] / cnt + bfc[0];
        out[g] = 1.f / (1.f + expf(-z));
    }
}

// ---------------- launcher ----------------

static inline int cdiv(int a, int b) { return (a + b - 1) / b; }

extern "C" void kernel_launch(void* const* d_in, const int* in_sizes, int n_in,
                              void* d_out, int out_size, void* d_ws, size_t ws_size,
                              hipStream_t stream) {
    const float* x   = (const float*)d_in[0];
    const int*   ei  = (const int*)d_in[1];
    const float* ew  = (const float*)d_in[2];
    const int*   bat = (const int*)d_in[3];
    const float* W1  = (const float*)d_in[4];
    const float* b1  = (const float*)d_in[5];
    const float* W2  = (const float*)d_in[6];
    const float* b2  = (const float*)d_in[7];
    const float* W3  = (const float*)d_in[8];
    const float* b3  = (const float*)d_in[9];
    const float* Wfc = (const float*)d_in[10];
    const float* bfc = (const float*)d_in[11];
    float* out = (float*)d_out;

    const int N  = in_sizes[3];
    const int E  = in_sizes[2];
    const int H0 = in_sizes[0] / N;   // 8
    const int H1 = in_sizes[5];       // 128
    const int H2 = in_sizes[7];       // 256
    const int G  = out_size;          // 256

    const int* srcv = ei;
    const int* dstv = ei + E;

    float* ws   = (float*)d_ws;
    float* dinv = ws;                       // N
    float* nrm  = dinv + N;                 // E
    float* bufA = nrm + E;                  // N * H2 (max agg width = 256)
    float* bufB = bufA + (size_t)N * H2;    // N * H3 (max feature width = 512)

    // degree -> dinv -> per-edge norm
    k_init_deg<<<cdiv(N, 256), 256, 0, stream>>>(dinv, N);
    k_deg_acc<<<cdiv(E, 256), 256, 0, stream>>>(dstv, ew, dinv, E);
    k_dinv<<<cdiv(N, 256), 256, 0, stream>>>(dinv, N);
    k_norm<<<cdiv(E, 256), 256, 0, stream>>>(srcv, dstv, ew, dinv, nrm, E);

    // ---- layer 1: agg(x)[N,8] -> relu(agg@W1 + b1)[N,128] in bufB
    {
        int F = H0, sh = __builtin_ctz(F);
        k_self<<<cdiv(N * F, 256), 256, 0, stream>>>(x, dinv, bufA, N * F, sh);
        long long tot = (long long)E * F;
        k_edge<<<(int)((tot + 255) / 256), 256, 0, stream>>>(srcv, dstv, nrm, x, bufA, tot, sh, F - 1);
        dim3 grid(cdiv(N, 128), H1 / 128);
        k_gemm_bias_relu<8><<<grid, 256, 0, stream>>>(bufA, W1, b1, bufB, N, H0, H1);
    }
    // ---- layer 2: agg(h1)[N,128] -> relu(@W2 + b2)[N,256] in bufB
    {
        int F = H1, sh = __builtin_ctz(F);
        k_self<<<cdiv(N * F, 256), 256, 0, stream>>>(bufB, dinv, bufA, N * F, sh);
        long long tot = (long long)E * F;
        k_edge<<<(int)((tot + 255) / 256), 256, 0, stream>>>(srcv, dstv, nrm, bufB, bufA, tot, sh, F - 1);
        dim3 grid(cdiv(N, 128), H2 / 128);
        k_gemm_bias_relu<16><<<grid, 256, 0, stream>>>(bufA, W2, b2, bufB, N, H1, H2);
    }
    // ---- layer 3: agg(h2)[N,256] -> relu(@W3 + b3)[N,512] in bufB
    {
        int F = H2, sh = __builtin_ctz(F);
        k_self<<<cdiv(N * F, 256), 256, 0, stream>>>(bufB, dinv, bufA, N * F, sh);
        long long tot = (long long)E * F;
        k_edge<<<(int)((tot + 255) / 256), 256, 0, stream>>>(srcv, dstv, nrm, bufB, bufA, tot, sh, F - 1);
        dim3 grid(cdiv(N, 128), in_sizes[9] / 128);
        k_gemm_bias_relu<16><<<grid, 256, 0, stream>>>(bufA, W3, b3, bufB, N, H2, in_sizes[9]);
    }

    // ---- mean-pool per graph + FC + sigmoid
    k_pool_fc<<<G, 256, 0, stream>>>(bufB, bat, Wfc, bfc, out, N);
}

// Round 2
// 551.845 us; speedup vs baseline: 1.3826x; 1.3826x over previous
//
#include <hip/hip_runtime.h>
#include <math.h>

typedef __attribute__((ext_vector_type(8))) short short8;
typedef __attribute__((ext_vector_type(4))) float floatx4;

// ---------------- bf16 split helpers ----------------

__device__ __forceinline__ unsigned short f2bf(float f) {
    unsigned int u = __float_as_uint(f);
    unsigned int r = (u + 0x7fffu + ((u >> 16) & 1u)) >> 16;  // RNE
    return (unsigned short)r;
}
__device__ __forceinline__ float bf2f(unsigned short h) {
    return __uint_as_float((unsigned int)h << 16);
}

// ---------------- degree / norm precompute ----------------

__global__ void k_init_deg(float* __restrict__ deg, int N) {
    int i = blockIdx.x * blockDim.x + threadIdx.x;
    if (i < N) deg[i] = 1.0f;  // self-loop weight
}

__global__ void k_deg_acc(const int* __restrict__ dst, const float* __restrict__ ew,
                          float* __restrict__ deg, int E) {
    int e = blockIdx.x * blockDim.x + threadIdx.x;
    if (e < E) atomicAdd(&deg[dst[e]], ew[e]);
}

__global__ void k_dinv(float* __restrict__ deg, int N) {
    int i = blockIdx.x * blockDim.x + threadIdx.x;
    if (i < N) deg[i] = rsqrtf(deg[i]);  // deg >= 1 guaranteed (self-loop)
}

__global__ void k_norm(const int* __restrict__ src, const int* __restrict__ dst,
                       const float* __restrict__ ew, const float* __restrict__ dinv,
                       float* __restrict__ norm, int E) {
    int e = blockIdx.x * blockDim.x + threadIdx.x;
    if (e < E) norm[e] = dinv[src[e]] * ew[e] * dinv[dst[e]];
}

// ---------------- aggregation: agg = \hat{A} h (before the matmul) ----------------

__global__ void k_self(const float* __restrict__ h, const float* __restrict__ dinv,
                       float* __restrict__ agg, int total, int shiftF) {
    int i = blockIdx.x * blockDim.x + threadIdx.x;
    if (i < total) {
        int n = i >> shiftF;
        float dv = dinv[n];
        agg[i] = h[i] * dv * dv;
    }
}

__global__ void k_edge(const int* __restrict__ src, const int* __restrict__ dst,
                       const float* __restrict__ norm, const float* __restrict__ h,
                       float* __restrict__ agg, long long total, int shiftF, int maskF) {
    long long gid = (long long)blockIdx.x * blockDim.x + threadIdx.x;
    if (gid >= total) return;
    int e = (int)(gid >> shiftF);
    int f = (int)(gid & maskF);
    int s = src[e], d = dst[e];
    float v = h[(long long)s << shiftF | f] * norm[e];
    atomicAdd(&agg[(long long)d << shiftF | f], v);
}

// ---------------- weight pre-split: W[K,Fout] fp32 -> WT_hi/WT_lo[Fout,K] bf16 ----------------

__global__ void k_wt_split(const float* __restrict__ W, unsigned short* __restrict__ hi,
                           unsigned short* __restrict__ lo, int K, int Fout) {
    int gid = blockIdx.x * blockDim.x + threadIdx.x;
    if (gid >= K * Fout) return;
    int k = gid / Fout, n = gid % Fout;  // coalesced read along n
    float w = W[gid];
    unsigned short h = f2bf(w);
    unsigned short l = f2bf(w - bf2f(h));
    hi[(size_t)n * K + k] = h;
    lo[(size_t)n * K + k] = l;
}

// ---------------- bf16x3 MFMA GEMM: C = relu(A @ W + bias) ----------------
// A: [M,K] fp32 (split to hi/lo bf16 during LDS staging). WT: [Fout,K] bf16 pre-split.
// BM=BN=128, BK=32, 256 threads = 4 waves, each wave does 64x64 via 4x4 mfma_16x16x32.
// acc += Ahi*Bhi + Ahi*Blo + Alo*Bhi  (~fp32 precision, dropped term ~2^-18).

__global__ __launch_bounds__(256) void k_gemm_mfma3(
    const float* __restrict__ A, const unsigned short* __restrict__ WThi,
    const unsigned short* __restrict__ WTlo, const float* __restrict__ bias,
    float* __restrict__ C, int M, int K, int Fout) {
    const int LD = 40;  // bf16 elems per LDS row: 80 B, 16B-aligned, <=2-way bank alias (free)
    __shared__ unsigned short Ahi[128 * LD], Alo[128 * LD];
    __shared__ unsigned short Bhi[128 * LD], Blo[128 * LD];

    int tid = threadIdx.x;
    int bm = blockIdx.x * 128, bn = blockIdx.y * 128;
    int wave = tid >> 6, lane = tid & 63;
    int quad = lane >> 4, r = lane & 15;
    int wm = (wave & 1) * 64, wn = (wave >> 1) * 64;

    floatx4 acc[4][4] = {};

    for (int k0 = 0; k0 < K; k0 += 32) {
        // ---- stage A: 128 rows x 32 k fp32, convert to hi/lo bf16
#pragma unroll
        for (int i = tid; i < 1024; i += 256) {
            int row = i >> 3;
            int kq = (i & 7) << 2;
            int gm = bm + row;
            float4 v = make_float4(0.f, 0.f, 0.f, 0.f);
            if (gm < M) v = *(const float4*)&A[(size_t)gm * K + k0 + kq];
            ushort4 h, l;
            h.x = f2bf(v.x); l.x = f2bf(v.x - bf2f(h.x));
            h.y = f2bf(v.y); l.y = f2bf(v.y - bf2f(h.y));
            h.z = f2bf(v.z); l.z = f2bf(v.z - bf2f(h.z));
            h.w = f2bf(v.w); l.w = f2bf(v.w - bf2f(h.w));
            *(ushort4*)&Ahi[row * LD + kq] = h;
            *(ushort4*)&Alo[row * LD + kq] = l;
        }
        // ---- stage B: 128 n-rows x 32 k bf16, straight 16B copies
#pragma unroll
        for (int i = tid; i < 512; i += 256) {
            int n = i >> 2;
            int kc = (i & 3) << 3;
            *(uint4*)&Bhi[n * LD + kc] = *(const uint4*)&WThi[(size_t)(bn + n) * K + k0 + kc];
            *(uint4*)&Blo[n * LD + kc] = *(const uint4*)&WTlo[(size_t)(bn + n) * K + k0 + kc];
        }
        __syncthreads();

        short8 ah[4], al[4], bh[4], bl[4];
#pragma unroll
        for (int t = 0; t < 4; ++t) {
            int m = wm + t * 16 + r;
            ah[t] = *(const short8*)&Ahi[m * LD + quad * 8];
            al[t] = *(const short8*)&Alo[m * LD + quad * 8];
            int n = wn + t * 16 + r;
            bh[t] = *(const short8*)&Bhi[n * LD + quad * 8];
            bl[t] = *(const short8*)&Blo[n * LD + quad * 8];
        }
#pragma unroll
        for (int mt = 0; mt < 4; ++mt)
#pragma unroll
            for (int nt = 0; nt < 4; ++nt) {
                acc[mt][nt] = __builtin_amdgcn_mfma_f32_16x16x32_bf16(ah[mt], bh[nt], acc[mt][nt], 0, 0, 0);
                acc[mt][nt] = __builtin_amdgcn_mfma_f32_16x16x32_bf16(ah[mt], bl[nt], acc[mt][nt], 0, 0, 0);
                acc[mt][nt] = __builtin_amdgcn_mfma_f32_16x16x32_bf16(al[mt], bh[nt], acc[mt][nt], 0, 0, 0);
            }
        __syncthreads();
    }

    // ---- epilogue: bias + relu. C/D layout: col=lane&15 (n), row=quad*4+reg (m).
#pragma unroll
    for (int nt = 0; nt < 4; ++nt) {
        int gn = bn + wn + nt * 16 + r;
        float bv = bias[gn];
#pragma unroll
        for (int mt = 0; mt < 4; ++mt) {
#pragma unroll
            for (int reg = 0; reg < 4; ++reg) {
                int gm = bm + wm + mt * 16 + quad * 4 + reg;
                if (gm < M) C[(size_t)gm * Fout + gn] = fmaxf(acc[mt][nt][reg] + bv, 0.f);
            }
        }
    }
}

// ---------------- fp32 tiled GEMM (layer 1 only, K=8) ----------------

template <int BK>
__global__ __launch_bounds__(256) void k_gemm_bias_relu(
    const float* __restrict__ A, const float* __restrict__ W,
    const float* __restrict__ bias, float* __restrict__ C,
    int M, int K, int Fout) {
    const int BM = 128, BN = 128;
    __shared__ float As[BK][BM + 4];
    __shared__ float Bs[BK][BN];

    int bm = blockIdx.x * BM;
    int bn = blockIdx.y * BN;
    int tid = threadIdx.x;
    int tx = tid & 15;
    int ty = tid >> 4;

    float acc[8][8];
#pragma unroll
    for (int i = 0; i < 8; ++i)
#pragma unroll
        for (int j = 0; j < 8; ++j) acc[i][j] = 0.f;

    for (int k0 = 0; k0 < K; k0 += BK) {
#pragma unroll
        for (int i = tid; i < BM * BK; i += 256) {
            int k = i % BK;
            int m = i / BK;
            int gm = bm + m;
            As[k][m] = (gm < M) ? A[(long long)gm * K + k0 + k] : 0.f;
        }
#pragma unroll
        for (int i = tid; i < BK * BN; i += 256) {
            int n = i % BN;
            int k = i / BN;
            Bs[k][n] = W[(long long)(k0 + k) * Fout + bn + n];
        }
        __syncthreads();

#pragma unroll
        for (int k = 0; k < BK; ++k) {
            float a[8], b[8];
            float4 a0 = *(const float4*)&As[k][ty * 4];
            float4 a1 = *(const float4*)&As[k][ty * 4 + 64];
            float4 b0 = *(const float4*)&Bs[k][tx * 4];
            float4 b1 = *(const float4*)&Bs[k][tx * 4 + 64];
            a[0] = a0.x; a[1] = a0.y; a[2] = a0.z; a[3] = a0.w;
            a[4] = a1.x; a[5] = a1.y; a[6] = a1.z; a[7] = a1.w;
            b[0] = b0.x; b[1] = b0.y; b[2] = b0.z; b[3] = b0.w;
            b[4] = b1.x; b[5] = b1.y; b[6] = b1.z; b[7] = b1.w;
#pragma unroll
            for (int i = 0; i < 8; ++i)
#pragma unroll
                for (int j = 0; j < 8; ++j) acc[i][j] += a[i] * b[j];
        }
        __syncthreads();
    }

    float4 bi0 = *(const float4*)&bias[bn + tx * 4];
    float4 bi1 = *(const float4*)&bias[bn + tx * 4 + 64];
    float bb[8] = {bi0.x, bi0.y, bi0.z, bi0.w, bi1.x, bi1.y, bi1.z, bi1.w};
#pragma unroll
    for (int i = 0; i < 8; ++i) {
        int gm = bm + ((i < 4) ? (ty * 4 + i) : (64 + ty * 4 + i - 4));
        if (gm >= M) continue;
        float4 v0, v1;
        float* v0p = &v0.x;
        float* v1p = &v1.x;
#pragma unroll
        for (int j = 0; j < 4; ++j) {
            v0p[j] = fmaxf(acc[i][j] + bb[j], 0.f);
            v1p[j] = fmaxf(acc[i][j + 4] + bb[j + 4], 0.f);
        }
        *(float4*)&C[(long long)gm * Fout + bn + tx * 4] = v0;
        *(float4*)&C[(long long)gm * Fout + bn + tx * 4 + 64] = v1;
    }
}

// ---------------- fused mean-pool + FC + sigmoid ----------------

__global__ __launch_bounds__(256) void k_pool_fc(
    const float* __restrict__ h3, const int* __restrict__ batch,
    const float* __restrict__ Wfc, const float* __restrict__ bfc,
    float* __restrict__ out, int N) {
    int g = blockIdx.x;
    int t = threadIdx.x;

    int lo = 0, hi = N;
    while (lo < hi) { int mid = (lo + hi) >> 1; if (batch[mid] < g) lo = mid + 1; else hi = mid; }
    int start = lo;
    hi = N;
    while (lo < hi) { int mid = (lo + hi) >> 1; if (batch[mid] < g + 1) lo = mid + 1; else hi = mid; }
    int end = lo;

    float acc0 = 0.f, acc1 = 0.f;
    for (int n = start; n < end; ++n) {
        acc0 += h3[(long long)n * 512 + t];
        acc1 += h3[(long long)n * 512 + t + 256];
    }
    float partial = acc0 * Wfc[t] + acc1 * Wfc[t + 256];

    __shared__ float red[256];
    red[t] = partial;
    __syncthreads();
    for (int s = 128; s > 0; s >>= 1) {
        if (t < s) red[t] += red[t + s];
        __syncthreads();
    }
    if (t == 0) {
        float cnt = (float)(end - start);
        if (cnt < 1.f) cnt = 1.f;
        float z = red[0] / cnt + bfc[0];
        out[g] = 1.f / (1.f + expf(-z));
    }
}

// ---------------- launcher ----------------

static inline int cdiv(int a, int b) { return (a + b - 1) / b; }

extern "C" void kernel_launch(void* const* d_in, const int* in_sizes, int n_in,
                              void* d_out, int out_size, void* d_ws, size_t ws_size,
                              hipStream_t stream) {
    const float* x   = (const float*)d_in[0];
    const int*   ei  = (const int*)d_in[1];
    const float* ew  = (const float*)d_in[2];
    const int*   bat = (const int*)d_in[3];
    const float* W1  = (const float*)d_in[4];
    const float* b1  = (const float*)d_in[5];
    const float* W2  = (const float*)d_in[6];
    const float* b2  = (const float*)d_in[7];
    const float* W3  = (const float*)d_in[8];
    const float* b3  = (const float*)d_in[9];
    const float* Wfc = (const float*)d_in[10];
    const float* bfc = (const float*)d_in[11];
    float* out = (float*)d_out;

    const int N  = in_sizes[3];
    const int E  = in_sizes[2];
    const int H0 = in_sizes[0] / N;   // 8
    const int H1 = in_sizes[5];       // 128
    const int H2 = in_sizes[7];       // 256
    const int H3 = in_sizes[9];       // 512
    const int G  = out_size;          // 256

    const int* srcv = ei;
    const int* dstv = ei + E;

    // workspace layout (all 16B-aligned given sizes)
    char* p = (char*)d_ws;
    float* dinv = (float*)p;            p += (size_t)N * 4;          // 200000 B
    float* nrm  = (float*)p;            p += (size_t)E * 4;          // 600000 B
    unsigned short* WT2hi = (unsigned short*)p; p += (size_t)H1 * H2 * 2;
    unsigned short* WT2lo = (unsigned short*)p; p += (size_t)H1 * H2 * 2;
    unsigned short* WT3hi = (unsigned short*)p; p += (size_t)H2 * H3 * 2;
    unsigned short* WT3lo = (unsigned short*)p; p += (size_t)H2 * H3 * 2;
    float* bufA = (float*)p;            p += (size_t)N * H2 * 4;     // max agg width 256
    float* bufB = (float*)p;                                          // max feat width 512

    // degree -> dinv -> per-edge norm
    k_init_deg<<<cdiv(N, 256), 256, 0, stream>>>(dinv, N);
    k_deg_acc<<<cdiv(E, 256), 256, 0, stream>>>(dstv, ew, dinv, E);
    k_dinv<<<cdiv(N, 256), 256, 0, stream>>>(dinv, N);
    k_norm<<<cdiv(E, 256), 256, 0, stream>>>(srcv, dstv, ew, dinv, nrm, E);

    // weight pre-split (tiny)
    k_wt_split<<<cdiv(H1 * H2, 256), 256, 0, stream>>>(W2, WT2hi, WT2lo, H1, H2);
    k_wt_split<<<cdiv(H2 * H3, 256), 256, 0, stream>>>(W3, WT3hi, WT3lo, H2, H3);

    // ---- layer 1: agg(x)[N,8] -> relu(agg@W1 + b1)[N,128] in bufB  (fp32 path, K=8)
    {
        int F = H0, sh = __builtin_ctz(F);
        k_self<<<cdiv(N * F, 256), 256, 0, stream>>>(x, dinv, bufA, N * F, sh);
        long long tot = (long long)E * F;
        k_edge<<<(int)((tot + 255) / 256), 256, 0, stream>>>(srcv, dstv, nrm, x, bufA, tot, sh, F - 1);
        dim3 grid(cdiv(N, 128), H1 / 128);
        k_gemm_bias_relu<8><<<grid, 256, 0, stream>>>(bufA, W1, b1, bufB, N, H0, H1);
    }
    // ---- layer 2: agg(h1)[N,128] -> relu(@W2 + b2)[N,256] in bufB  (MFMA bf16x3)
    {
        int F = H1, sh = __builtin_ctz(F);
        k_self<<<cdiv(N * F, 256), 256, 0, stream>>>(bufB, dinv, bufA, N * F, sh);
        long long tot = (long long)E * F;
        k_edge<<<(int)((tot + 255) / 256), 256, 0, stream>>>(srcv, dstv, nrm, bufB, bufA, tot, sh, F - 1);
        dim3 grid(cdiv(N, 128), H2 / 128);
        k_gemm_mfma3<<<grid, 256, 0, stream>>>(bufA, WT2hi, WT2lo, b2, bufB, N, H1, H2);
    }
    // ---- layer 3: agg(h2)[N,256] -> relu(@W3 + b3)[N,512] in bufB  (MFMA bf16x3)
    {
        int F = H2, sh = __builtin_ctz(F);
        k_self<<<cdiv(N * F, 256), 256, 0, stream>>>(bufB, dinv, bufA, N * F, sh);
        long long tot = (long long)E * F;
        k_edge<<<(int)((tot + 255) / 256), 256, 0, stream>>>(srcv, dstv, nrm, bufB, bufA, tot, sh, F - 1);
        dim3 grid(cdiv(N, 128), H3 / 128);
        k_gemm_mfma3<<<grid, 256, 0, stream>>>(bufA, WT3hi, WT3lo, b3, bufB, N, H2, H3);
    }

    // ---- mean-pool per graph + FC + sigmoid
    k_pool_fc<<<G, 256, 0, stream>>>(bufB, bat, Wfc, bfc, out, N);
}

// Round 3
// 441.903 us; speedup vs baseline: 1.7265x; 1.2488x over previous
//
#include <hip/hip_runtime.h>
#include <math.h>

typedef __attribute__((ext_vector_type(8))) short short8;
typedef __attribute__((ext_vector_type(4))) float floatx4;

// ---------------- bf16 split helpers ----------------

__device__ __forceinline__ unsigned short f2bf(float f) {
    unsigned int u = __float_as_uint(f);
    unsigned int r = (u + 0x7fffu + ((u >> 16) & 1u)) >> 16;  // RNE
    return (unsigned short)r;
}
__device__ __forceinline__ float bf2f(unsigned short h) {
    return __uint_as_float((unsigned int)h << 16);
}

// ---------------- precompute: deg/dinv/norm + dst histogram ----------------

__global__ void k_init(float* __restrict__ deg, int* __restrict__ cnt,
                       int* __restrict__ cursor, int N) {
    int i = blockIdx.x * blockDim.x + threadIdx.x;
    if (i < N) { deg[i] = 1.0f; cnt[i] = 0; cursor[i] = 0; }
}

__global__ void k_hist_deg(const int* __restrict__ dst, const float* __restrict__ ew,
                           float* __restrict__ deg, int* __restrict__ cnt, int E) {
    int e = blockIdx.x * blockDim.x + threadIdx.x;
    if (e < E) {
        int d = dst[e];
        atomicAdd(&deg[d], ew[e]);
        atomicAdd(&cnt[d], 1);
    }
}

__global__ void k_dinv(float* __restrict__ deg, int N) {
    int i = blockIdx.x * blockDim.x + threadIdx.x;
    if (i < N) deg[i] = rsqrtf(deg[i]);  // deg >= 1 (self-loop)
}

__global__ void k_norm(const int* __restrict__ src, const int* __restrict__ dst,
                       const float* __restrict__ ew, const float* __restrict__ dinv,
                       float* __restrict__ norm, int E) {
    int e = blockIdx.x * blockDim.x + threadIdx.x;
    if (e < E) norm[e] = dinv[src[e]] * ew[e] * dinv[dst[e]];
}

// ---------------- exclusive scan of cnt[N] -> row_start[N+1] (3 kernels) ----------------

__global__ __launch_bounds__(256) void k_scan_a(const int* __restrict__ cnt,
                                                int* __restrict__ bsum, int N) {
    int b = blockIdx.x, t = threadIdx.x;
    int base = b * 1024 + t * 4;
    int s = 0;
#pragma unroll
    for (int j = 0; j < 4; ++j) { int i = base + j; if (i < N) s += cnt[i]; }
    __shared__ int sh[256];
    sh[t] = s; __syncthreads();
    for (int st = 128; st > 0; st >>= 1) { if (t < st) sh[t] += sh[t + st]; __syncthreads(); }
    if (t == 0) bsum[b] = sh[0];
}

__global__ __launch_bounds__(256) void k_scan_b(int* __restrict__ bsum, int nb) {
    int t = threadIdx.x;
    __shared__ int sh[256];
    int orig = (t < nb) ? bsum[t] : 0;
    sh[t] = orig; __syncthreads();
    for (int off = 1; off < 256; off <<= 1) {
        int x = (t >= off) ? sh[t - off] : 0;
        __syncthreads();
        sh[t] += x;
        __syncthreads();
    }
    if (t < nb) bsum[t] = sh[t] - orig;  // exclusive
}

__global__ __launch_bounds__(256) void k_scan_c(const int* __restrict__ cnt,
                                                const int* __restrict__ boff,
                                                int* __restrict__ row_start, int N) {
    int b = blockIdx.x, t = threadIdx.x;
    int base = b * 1024 + t * 4;
    int v[4]; int s = 0;
#pragma unroll
    for (int j = 0; j < 4; ++j) { int i = base + j; v[j] = (i < N) ? cnt[i] : 0; s += v[j]; }
    __shared__ int sh[256];
    sh[t] = s; __syncthreads();
    for (int off = 1; off < 256; off <<= 1) {
        int x = (t >= off) ? sh[t - off] : 0;
        __syncthreads();
        sh[t] += x;
        __syncthreads();
    }
    int excl = sh[t] - s + boff[b];
#pragma unroll
    for (int j = 0; j < 4; ++j) {
        int i = base + j;
        if (i < N) row_start[i] = excl;
        excl += v[j];
        if (i == N - 1) row_start[N] = excl;
    }
}

__global__ void k_scatter(const int* __restrict__ src, const int* __restrict__ dst,
                          const float* __restrict__ nrm, const int* __restrict__ row_start,
                          int* __restrict__ cursor, int* __restrict__ esrc,
                          float* __restrict__ enorm, int E) {
    int e = blockIdx.x * blockDim.x + threadIdx.x;
    if (e >= E) return;
    int d = dst[e];
    int pos = row_start[d] + atomicAdd(&cursor[d], 1);
    esrc[pos] = src[e];
    enorm[pos] = nrm[e];
}

// ---------------- fused aggregation (self-loop + CSR gather, no atomics) ----------------
// out[n][f] = h[n][f]*dinv[n]^2 + sum_j enorm[j] * h[esrc[j]][f]

__global__ void k_agg(const float* __restrict__ h, const float* __restrict__ dinv,
                      const int* __restrict__ esrc, const float* __restrict__ enorm,
                      const int* __restrict__ row_start, float* __restrict__ out,
                      int N, int shiftF, int maskF) {
    int gid = blockIdx.x * blockDim.x + threadIdx.x;
    if (gid >= (N << shiftF)) return;
    int n = gid >> shiftF;
    int f = gid & maskF;
    float dv = dinv[n];
    float acc = h[gid] * dv * dv;
    int s0 = row_start[n], s1 = row_start[n + 1];
    for (int j = s0; j < s1; ++j)
        acc += enorm[j] * h[((size_t)esrc[j] << shiftF) | f];
    out[gid] = acc;
}

// ---------------- weight pre-split: W[K,Fout] fp32 -> WT_hi/WT_lo[Fout,K] bf16 ----------------

__global__ void k_wt_split(const float* __restrict__ W, unsigned short* __restrict__ hi,
                           unsigned short* __restrict__ lo, int K, int Fout) {
    int gid = blockIdx.x * blockDim.x + threadIdx.x;
    if (gid >= K * Fout) return;
    int k = gid / Fout, n = gid % Fout;
    float w = W[gid];
    unsigned short h = f2bf(w);
    unsigned short l = f2bf(w - bf2f(h));
    hi[(size_t)n * K + k] = h;
    lo[(size_t)n * K + k] = l;
}

// ---------------- bf16x3 MFMA GEMM: C = relu(A @ W + bias) ----------------

__global__ __launch_bounds__(256) void k_gemm_mfma3(
    const float* __restrict__ A, const unsigned short* __restrict__ WThi,
    const unsigned short* __restrict__ WTlo, const float* __restrict__ bias,
    float* __restrict__ C, int M, int K, int Fout) {
    const int LD = 40;  // 80 B rows: 16B-aligned, <=2-way bank alias (free)
    __shared__ unsigned short Ahi[128 * LD], Alo[128 * LD];
    __shared__ unsigned short Bhi[128 * LD], Blo[128 * LD];

    int tid = threadIdx.x;
    int bm = blockIdx.x * 128, bn = blockIdx.y * 128;
    int wave = tid >> 6, lane = tid & 63;
    int quad = lane >> 4, r = lane & 15;
    int wm = (wave & 1) * 64, wn = (wave >> 1) * 64;

    floatx4 acc[4][4] = {};

    for (int k0 = 0; k0 < K; k0 += 32) {
#pragma unroll
        for (int i = tid; i < 1024; i += 256) {
            int row = i >> 3;
            int kq = (i & 7) << 2;
            int gm = bm + row;
            float4 v = make_float4(0.f, 0.f, 0.f, 0.f);
            if (gm < M) v = *(const float4*)&A[(size_t)gm * K + k0 + kq];
            ushort4 h, l;
            h.x = f2bf(v.x); l.x = f2bf(v.x - bf2f(h.x));
            h.y = f2bf(v.y); l.y = f2bf(v.y - bf2f(h.y));
            h.z = f2bf(v.z); l.z = f2bf(v.z - bf2f(h.z));
            h.w = f2bf(v.w); l.w = f2bf(v.w - bf2f(h.w));
            *(ushort4*)&Ahi[row * LD + kq] = h;
            *(ushort4*)&Alo[row * LD + kq] = l;
        }
#pragma unroll
        for (int i = tid; i < 512; i += 256) {
            int n = i >> 2;
            int kc = (i & 3) << 3;
            *(uint4*)&Bhi[n * LD + kc] = *(const uint4*)&WThi[(size_t)(bn + n) * K + k0 + kc];
            *(uint4*)&Blo[n * LD + kc] = *(const uint4*)&WTlo[(size_t)(bn + n) * K + k0 + kc];
        }
        __syncthreads();

        short8 ah[4], al[4], bh[4], bl[4];
#pragma unroll
        for (int t = 0; t < 4; ++t) {
            int m = wm + t * 16 + r;
            ah[t] = *(const short8*)&Ahi[m * LD + quad * 8];
            al[t] = *(const short8*)&Alo[m * LD + quad * 8];
            int n = wn + t * 16 + r;
            bh[t] = *(const short8*)&Bhi[n * LD + quad * 8];
            bl[t] = *(const short8*)&Blo[n * LD + quad * 8];
        }
#pragma unroll
        for (int mt = 0; mt < 4; ++mt)
#pragma unroll
            for (int nt = 0; nt < 4; ++nt) {
                acc[mt][nt] = __builtin_amdgcn_mfma_f32_16x16x32_bf16(ah[mt], bh[nt], acc[mt][nt], 0, 0, 0);
                acc[mt][nt] = __builtin_amdgcn_mfma_f32_16x16x32_bf16(ah[mt], bl[nt], acc[mt][nt], 0, 0, 0);
                acc[mt][nt] = __builtin_amdgcn_mfma_f32_16x16x32_bf16(al[mt], bh[nt], acc[mt][nt], 0, 0, 0);
            }
        __syncthreads();
    }

    // epilogue: bias + relu. C/D layout: col=lane&15 (n), row=quad*4+reg (m).
#pragma unroll
    for (int nt = 0; nt < 4; ++nt) {
        int gn = bn + wn + nt * 16 + r;
        float bv = bias[gn];
#pragma unroll
        for (int mt = 0; mt < 4; ++mt) {
#pragma unroll
            for (int reg = 0; reg < 4; ++reg) {
                int gm = bm + wm + mt * 16 + quad * 4 + reg;
                if (gm < M) C[(size_t)gm * Fout + gn] = fmaxf(acc[mt][nt][reg] + bv, 0.f);
            }
        }
    }
}

// ---------------- fp32 tiled GEMM (layer 1 only, K=8) ----------------

template <int BK>
__global__ __launch_bounds__(256) void k_gemm_bias_relu(
    const float* __restrict__ A, const float* __restrict__ W,
    const float* __restrict__ bias, float* __restrict__ C,
    int M, int K, int Fout) {
    const int BM = 128, BN = 128;
    __shared__ float As[BK][BM + 4];
    __shared__ float Bs[BK][BN];

    int bm = blockIdx.x * BM;
    int bn = blockIdx.y * BN;
    int tid = threadIdx.x;
    int tx = tid & 15;
    int ty = tid >> 4;

    float acc[8][8];
#pragma unroll
    for (int i = 0; i < 8; ++i)
#pragma unroll
        for (int j = 0; j < 8; ++j) acc[i][j] = 0.f;

    for (int k0 = 0; k0 < K; k0 += BK) {
#pragma unroll
        for (int i = tid; i < BM * BK; i += 256) {
            int k = i % BK;
            int m = i / BK;
            int gm = bm + m;
            As[k][m] = (gm < M) ? A[(long long)gm * K + k0 + k] : 0.f;
        }
#pragma unroll
        for (int i = tid; i < BK * BN; i += 256) {
            int n = i % BN;
            int k = i / BN;
            Bs[k][n] = W[(long long)(k0 + k) * Fout + bn + n];
        }
        __syncthreads();

#pragma unroll
        for (int k = 0; k < BK; ++k) {
            float a[8], b[8];
            float4 a0 = *(const float4*)&As[k][ty * 4];
            float4 a1 = *(const float4*)&As[k][ty * 4 + 64];
            float4 b0 = *(const float4*)&Bs[k][tx * 4];
            float4 b1 = *(const float4*)&Bs[k][tx * 4 + 64];
            a[0] = a0.x; a[1] = a0.y; a[2] = a0.z; a[3] = a0.w;
            a[4] = a1.x; a[5] = a1.y; a[6] = a1.z; a[7] = a1.w;
            b[0] = b0.x; b[1] = b0.y; b[2] = b0.z; b[3] = b0.w;
            b[4] = b1.x; b[5] = b1.y; b[6] = b1.z; b[7] = b1.w;
#pragma unroll
            for (int i = 0; i < 8; ++i)
#pragma unroll
                for (int j = 0; j < 8; ++j) acc[i][j] += a[i] * b[j];
        }
        __syncthreads();
    }

    float4 bi0 = *(const float4*)&bias[bn + tx * 4];
    float4 bi1 = *(const float4*)&bias[bn + tx * 4 + 64];
    float bb[8] = {bi0.x, bi0.y, bi0.z, bi0.w, bi1.x, bi1.y, bi1.z, bi1.w};
#pragma unroll
    for (int i = 0; i < 8; ++i) {
        int gm = bm + ((i < 4) ? (ty * 4 + i) : (64 + ty * 4 + i - 4));
        if (gm >= M) continue;
        float4 v0, v1;
        float* v0p = &v0.x;
        float* v1p = &v1.x;
#pragma unroll
        for (int j = 0; j < 4; ++j) {
            v0p[j] = fmaxf(acc[i][j] + bb[j], 0.f);
            v1p[j] = fmaxf(acc[i][j + 4] + bb[j + 4], 0.f);
        }
        *(float4*)&C[(long long)gm * Fout + bn + tx * 4] = v0;
        *(float4*)&C[(long long)gm * Fout + bn + tx * 4 + 64] = v1;
    }
}

// ---------------- pool stage 1: t[n] = h3[n,:512] . Wfc ----------------

__global__ __launch_bounds__(256) void k_dot(const float* __restrict__ h3,
                                             const float* __restrict__ Wfc,
                                             float* __restrict__ t, int N) {
    int wid = (int)((blockIdx.x * blockDim.x + threadIdx.x) >> 6);
    int lane = threadIdx.x & 63;
    if (wid >= N) return;
    const float* row = &h3[(size_t)wid * 512];
    float4 a0 = *(const float4*)&row[lane * 4];
    float4 a1 = *(const float4*)&row[lane * 4 + 256];
    float4 w0 = *(const float4*)&Wfc[lane * 4];
    float4 w1 = *(const float4*)&Wfc[lane * 4 + 256];
    float s = a0.x * w0.x + a0.y * w0.y + a0.z * w0.z + a0.w * w0.w
            + a1.x * w1.x + a1.y * w1.y + a1.z * w1.z + a1.w * w1.w;
#pragma unroll
    for (int off = 32; off > 0; off >>= 1) s += __shfl_down(s, off);
    if (lane == 0) t[wid] = s;
}

// ---------------- pool stage 2: segment mean + sigmoid (wave per graph) ----------------

__global__ __launch_bounds__(256) void k_pool2(const float* __restrict__ t,
                                               const int* __restrict__ batch,
                                               const float* __restrict__ bfc,
                                               float* __restrict__ out, int N, int G) {
    int g = (int)((blockIdx.x * blockDim.x + threadIdx.x) >> 6);
    int lane = threadIdx.x & 63;
    if (g >= G) return;
    int lo = 0, hi = N;
    while (lo < hi) { int m = (lo + hi) >> 1; if (batch[m] < g) lo = m + 1; else hi = m; }
    int start = lo;
    hi = N;
    while (lo < hi) { int m = (lo + hi) >> 1; if (batch[m] < g + 1) lo = m + 1; else hi = m; }
    int end = lo;
    float s = 0.f;
    for (int i = start + lane; i < end; i += 64) s += t[i];
#pragma unroll
    for (int off = 32; off > 0; off >>= 1) s += __shfl_down(s, off);
    if (lane == 0) {
        float c = (float)(end - start);
        if (c < 1.f) c = 1.f;
        float z = s / c + bfc[0];
        out[g] = 1.f / (1.f + expf(-z));
    }
}

// ---------------- launcher ----------------

static inline int cdiv(int a, int b) { return (a + b - 1) / b; }

extern "C" void kernel_launch(void* const* d_in, const int* in_sizes, int n_in,
                              void* d_out, int out_size, void* d_ws, size_t ws_size,
                              hipStream_t stream) {
    const float* x   = (const float*)d_in[0];
    const int*   ei  = (const int*)d_in[1];
    const float* ew  = (const float*)d_in[2];
    const int*   bat = (const int*)d_in[3];
    const float* W1  = (const float*)d_in[4];
    const float* b1  = (const float*)d_in[5];
    const float* W2  = (const float*)d_in[6];
    const float* b2  = (const float*)d_in[7];
    const float* W3  = (const float*)d_in[8];
    const float* b3  = (const float*)d_in[9];
    const float* Wfc = (const float*)d_in[10];
    const float* bfc = (const float*)d_in[11];
    float* out = (float*)d_out;

    const int N  = in_sizes[3];
    const int E  = in_sizes[2];
    const int H0 = in_sizes[0] / N;   // 8
    const int H1 = in_sizes[5];       // 128
    const int H2 = in_sizes[7];       // 256
    const int H3 = in_sizes[9];       // 512
    const int G  = out_size;          // 256
    const int Npad = (N + 4) & ~3;    // 16B-aligned slot for N+1 ints

    const int* srcv = ei;
    const int* dstv = ei + E;

    char* p = (char*)d_ws;
    float* dinv      = (float*)p; p += (size_t)N * 4;
    float* nrm       = (float*)p; p += (size_t)E * 4;
    int*   cnt       = (int*)p;   p += (size_t)N * 4;
    int*   cursor    = (int*)p;   p += (size_t)N * 4;
    int*   bsum      = (int*)p;   p += 256 * 4;
    int*   row_start = (int*)p;   p += (size_t)Npad * 4;
    int*   esrc      = (int*)p;   p += (size_t)E * 4;
    float* enorm     = (float*)p; p += (size_t)E * 4;
    float* tbuf      = (float*)p; p += (size_t)N * 4;
    unsigned short* WT2hi = (unsigned short*)p; p += (size_t)H1 * H2 * 2;
    unsigned short* WT2lo = (unsigned short*)p; p += (size_t)H1 * H2 * 2;
    unsigned short* WT3hi = (unsigned short*)p; p += (size_t)H2 * H3 * 2;
    unsigned short* WT3lo = (unsigned short*)p; p += (size_t)H2 * H3 * 2;
    float* bufA = (float*)p;      p += (size_t)N * H2 * 4;  // max agg width 256
    float* bufB = (float*)p;                                 // max feat width 512

    // ---- precompute: deg/cnt -> dinv -> norm; CSR build
    k_init<<<cdiv(N, 256), 256, 0, stream>>>(dinv, cnt, cursor, N);
    k_hist_deg<<<cdiv(E, 256), 256, 0, stream>>>(dstv, ew, dinv, cnt, E);
    k_dinv<<<cdiv(N, 256), 256, 0, stream>>>(dinv, N);
    k_norm<<<cdiv(E, 256), 256, 0, stream>>>(srcv, dstv, ew, dinv, nrm, E);

    int nb = cdiv(N, 1024);
    k_scan_a<<<nb, 256, 0, stream>>>(cnt, bsum, N);
    k_scan_b<<<1, 256, 0, stream>>>(bsum, nb);
    k_scan_c<<<nb, 256, 0, stream>>>(cnt, bsum, row_start, N);
    k_scatter<<<cdiv(E, 256), 256, 0, stream>>>(srcv, dstv, nrm, row_start, cursor, esrc, enorm, E);

    // weight pre-split (tiny)
    k_wt_split<<<cdiv(H1 * H2, 256), 256, 0, stream>>>(W2, WT2hi, WT2lo, H1, H2);
    k_wt_split<<<cdiv(H2 * H3, 256), 256, 0, stream>>>(W3, WT3hi, WT3lo, H2, H3);

    // ---- layer 1: agg(x)[N,8] -> relu(@W1+b1)[N,128]  (fp32 GEMM, K=8)
    {
        int sh = __builtin_ctz(H0);
        k_agg<<<cdiv(N << sh, 256), 256, 0, stream>>>(x, dinv, esrc, enorm, row_start, bufA, N, sh, H0 - 1);
        dim3 grid(cdiv(N, 128), H1 / 128);
        k_gemm_bias_relu<8><<<grid, 256, 0, stream>>>(bufA, W1, b1, bufB, N, H0, H1);
    }
    // ---- layer 2: agg(h1)[N,128] -> relu(@W2+b2)[N,256]  (MFMA bf16x3)
    {
        int sh = __builtin_ctz(H1);
        k_agg<<<cdiv(N << sh, 256), 256, 0, stream>>>(bufB, dinv, esrc, enorm, row_start, bufA, N, sh, H1 - 1);
        dim3 grid(cdiv(N, 128), H2 / 128);
        k_gemm_mfma3<<<grid, 256, 0, stream>>>(bufA, WT2hi, WT2lo, b2, bufB, N, H1, H2);
    }
    // ---- layer 3: agg(h2)[N,256] -> relu(@W3+b3)[N,512]  (MFMA bf16x3)
    {
        int sh = __builtin_ctz(H2);
        k_agg<<<cdiv(N << sh, 256), 256, 0, stream>>>(bufB, dinv, esrc, enorm, row_start, bufA, N, sh, H2 - 1);
        dim3 grid(cdiv(N, 128), H3 / 128);
        k_gemm_mfma3<<<grid, 256, 0, stream>>>(bufA, WT3hi, WT3lo, b3, bufB, N, H2, H3);
    }

    // ---- pool: per-row dot, then segment mean + sigmoid
    k_dot<<<cdiv(N * 64, 256), 256, 0, stream>>>(bufB, Wfc, tbuf, N);
    k_pool2<<<cdiv(G * 64, 256), 256, 0, stream>>>(tbuf, bat, bfc, out, N, G);
}

// Round 4
// 356.411 us; speedup vs baseline: 2.1407x; 1.2399x over previous
//
#include <hip/hip_runtime.h>
#include <math.h>

typedef __attribute__((ext_vector_type(8))) short short8;
typedef __attribute__((ext_vector_type(4))) float floatx4;

// ---------------- bf16 split helpers ----------------

__device__ __forceinline__ unsigned short f2bf(float f) {
    unsigned int u = __float_as_uint(f);
    unsigned int r = (u + 0x7fffu + ((u >> 16) & 1u)) >> 16;  // RNE
    return (unsigned short)r;
}
__device__ __forceinline__ float bf2f(unsigned short h) {
    return __uint_as_float((unsigned int)h << 16);
}

// ---------------- precompute: deg/dinv/norm + dst histogram ----------------

__global__ void k_init(float* __restrict__ deg, int* __restrict__ cnt,
                       int* __restrict__ cursor, int N) {
    int i = blockIdx.x * blockDim.x + threadIdx.x;
    if (i < N) { deg[i] = 1.0f; cnt[i] = 0; cursor[i] = 0; }
}

__global__ void k_hist_deg(const int* __restrict__ dst, const float* __restrict__ ew,
                           float* __restrict__ deg, int* __restrict__ cnt, int E) {
    int e = blockIdx.x * blockDim.x + threadIdx.x;
    if (e < E) {
        int d = dst[e];
        atomicAdd(&deg[d], ew[e]);
        atomicAdd(&cnt[d], 1);
    }
}

__global__ void k_dinv(float* __restrict__ deg, int N) {
    int i = blockIdx.x * blockDim.x + threadIdx.x;
    if (i < N) deg[i] = rsqrtf(deg[i]);  // deg >= 1 (self-loop)
}

__global__ void k_norm(const int* __restrict__ src, const int* __restrict__ dst,
                       const float* __restrict__ ew, const float* __restrict__ dinv,
                       float* __restrict__ norm, int E) {
    int e = blockIdx.x * blockDim.x + threadIdx.x;
    if (e < E) norm[e] = dinv[src[e]] * ew[e] * dinv[dst[e]];
}

// ---------------- exclusive scan of cnt[N] -> row_start[N+1] ----------------

__global__ __launch_bounds__(256) void k_scan_a(const int* __restrict__ cnt,
                                                int* __restrict__ bsum, int N) {
    int b = blockIdx.x, t = threadIdx.x;
    int base = b * 1024 + t * 4;
    int s = 0;
#pragma unroll
    for (int j = 0; j < 4; ++j) { int i = base + j; if (i < N) s += cnt[i]; }
    __shared__ int sh[256];
    sh[t] = s; __syncthreads();
    for (int st = 128; st > 0; st >>= 1) { if (t < st) sh[t] += sh[t + st]; __syncthreads(); }
    if (t == 0) bsum[b] = sh[0];
}

__global__ __launch_bounds__(256) void k_scan_b(int* __restrict__ bsum, int nb) {
    int t = threadIdx.x;
    __shared__ int sh[256];
    int orig = (t < nb) ? bsum[t] : 0;
    sh[t] = orig; __syncthreads();
    for (int off = 1; off < 256; off <<= 1) {
        int x = (t >= off) ? sh[t - off] : 0;
        __syncthreads();
        sh[t] += x;
        __syncthreads();
    }
    if (t < nb) bsum[t] = sh[t] - orig;  // exclusive
}

__global__ __launch_bounds__(256) void k_scan_c(const int* __restrict__ cnt,
                                                const int* __restrict__ boff,
                                                int* __restrict__ row_start, int N) {
    int b = blockIdx.x, t = threadIdx.x;
    int base = b * 1024 + t * 4;
    int v[4]; int s = 0;
#pragma unroll
    for (int j = 0; j < 4; ++j) { int i = base + j; v[j] = (i < N) ? cnt[i] : 0; s += v[j]; }
    __shared__ int sh[256];
    sh[t] = s; __syncthreads();
    for (int off = 1; off < 256; off <<= 1) {
        int x = (t >= off) ? sh[t - off] : 0;
        __syncthreads();
        sh[t] += x;
        __syncthreads();
    }
    int excl = sh[t] - s + boff[b];
#pragma unroll
    for (int j = 0; j < 4; ++j) {
        int i = base + j;
        if (i < N) row_start[i] = excl;
        excl += v[j];
        if (i == N - 1) row_start[N] = excl;
    }
}

__global__ void k_scatter(const int* __restrict__ src, const int* __restrict__ dst,
                          const float* __restrict__ nrm, const int* __restrict__ row_start,
                          int* __restrict__ cursor, int* __restrict__ esrc,
                          float* __restrict__ enorm, int E) {
    int e = blockIdx.x * blockDim.x + threadIdx.x;
    if (e >= E) return;
    int d = dst[e];
    int pos = row_start[d] + atomicAdd(&cursor[d], 1);
    esrc[pos] = src[e];
    enorm[pos] = nrm[e];
}

// ---------------- aggregation, fp32 output (layer 1, F=8) ----------------

__global__ void k_agg_f32(const float* __restrict__ h, const float* __restrict__ dinv,
                          const int* __restrict__ esrc, const float* __restrict__ enorm,
                          const int* __restrict__ row_start, float* __restrict__ out,
                          int N, int shiftF, int maskF) {
    int gid = blockIdx.x * blockDim.x + threadIdx.x;
    if (gid >= (N << shiftF)) return;
    int n = gid >> shiftF;
    int f = gid & maskF;
    float dv = dinv[n];
    float acc = h[gid] * dv * dv;
    int s0 = row_start[n], s1 = row_start[n + 1];
    for (int j = s0; j < s1; ++j)
        acc += enorm[j] * h[((size_t)esrc[j] << shiftF) | f];
    out[gid] = acc;
}

// ---------------- aggregation, split-bf16 output (layers 2/3) ----------------
// Writes Ahi/Alo [Mpad, F] bf16 (zeros for pad rows n >= N). 2 features/thread.

__global__ void k_agg_bf(const float* __restrict__ h, const float* __restrict__ dinv,
                         const int* __restrict__ esrc, const float* __restrict__ enorm,
                         const int* __restrict__ row_start,
                         unsigned short* __restrict__ Ahi, unsigned short* __restrict__ Alo,
                         int N, int Mpad, int F, int hsh) {
    int p = blockIdx.x * blockDim.x + threadIdx.x;
    int half = F >> 1;
    if (p >= Mpad * half) return;
    int n = p >> hsh;                 // hsh = ctz(F) - 1
    int fp = (p & (half - 1)) << 1;
    size_t oidx = (size_t)n * F + fp;
    if (n >= N) {
        *(ushort2*)&Ahi[oidx] = make_ushort2(0, 0);
        *(ushort2*)&Alo[oidx] = make_ushort2(0, 0);
        return;
    }
    float dv = dinv[n];
    float2 hv = *(const float2*)&h[oidx];
    float s0 = hv.x * dv * dv, s1 = hv.y * dv * dv;
    int j0 = row_start[n], j1 = row_start[n + 1];
    for (int j = j0; j < j1; ++j) {
        int s = esrc[j];
        float w = enorm[j];
        float2 nv = *(const float2*)&h[(size_t)s * F + fp];
        s0 += w * nv.x;
        s1 += w * nv.y;
    }
    unsigned short h0 = f2bf(s0), h1 = f2bf(s1);
    *(ushort2*)&Ahi[oidx] = make_ushort2(h0, h1);
    *(ushort2*)&Alo[oidx] = make_ushort2(f2bf(s0 - bf2f(h0)), f2bf(s1 - bf2f(h1)));
}

// ---------------- weight pre-split: W[K,Fout] fp32 -> WT_hi/WT_lo[Fout,K] bf16 ----------------

__global__ void k_wt_split(const float* __restrict__ W, unsigned short* __restrict__ hi,
                           unsigned short* __restrict__ lo, int K, int Fout) {
    int gid = blockIdx.x * blockDim.x + threadIdx.x;
    if (gid >= K * Fout) return;
    int k = gid / Fout, n = gid % Fout;
    float w = W[gid];
    unsigned short h = f2bf(w);
    unsigned short l = f2bf(w - bf2f(h));
    hi[(size_t)n * K + k] = h;
    lo[(size_t)n * K + k] = l;
}

// ---------------- bf16x3 MFMA GEMM with async LDS staging ----------------
// A pre-split [Mpad,K] bf16 hi/lo; WT pre-split [Fout,K] bf16 hi/lo.
// 128x128 tile, BK=32, 4 tiles x 8 KB = 32 KB LDS, global_load_lds width-16.
// acc += Ahi*Bhi + Ahi*Blo + Alo*Bhi  (~fp32 precision).

__global__ __launch_bounds__(256, 3) void k_gemm_async(
    const unsigned short* __restrict__ Ahi, const unsigned short* __restrict__ Alo,
    const unsigned short* __restrict__ Bhi, const unsigned short* __restrict__ Blo,
    const float* __restrict__ bias, float* __restrict__ C,
    int M, int K, int Fout) {
    __shared__ __align__(16) unsigned short smem[16384];  // 32 KB

    int tid = threadIdx.x, wave = tid >> 6, lane = tid & 63;
    int quad = lane >> 4, r = lane & 15;
    int bm = blockIdx.x * 128, bn = blockIdx.y * 128;
    int wm = (wave & 1) * 64, wn = (wave >> 1) * 64;

    const unsigned short* gsrc[4] = {Ahi, Alo, Bhi, Blo};
    const int rb[4] = {bm, bm, bn, bn};

    floatx4 acc[4][4] = {};

    for (int k0 = 0; k0 < K; k0 += 32) {
        // stage 4 tiles (128 rows x 32 bf16 each), 2 chunks of 1 KB per wave per tile
#pragma unroll
        for (int t = 0; t < 4; ++t) {
#pragma unroll
            for (int i = 0; i < 2; ++i) {
                int q = wave * 2 + i;                 // wave-uniform chunk id
                int idx = q * 64 + lane;              // lane's 16B slot within tile
                int row = idx >> 2, kofs = (idx & 3) << 3;
                const unsigned short* g = gsrc[t] + ((size_t)(rb[t] + row) * K + k0 + kofs);
                unsigned short* l = &smem[t * 4096 + q * 512];  // wave-uniform base; HW adds lane*16
                __builtin_amdgcn_global_load_lds(
                    (const __attribute__((address_space(1))) void*)g,
                    (__attribute__((address_space(3))) void*)l, 16, 0, 0);
            }
        }
        __syncthreads();

        short8 ah[4], al[4];
#pragma unroll
        for (int mt = 0; mt < 4; ++mt) {
            int m = wm + mt * 16 + r;
            ah[mt] = *(const short8*)&smem[m * 32 + quad * 8];
            al[mt] = *(const short8*)&smem[4096 + m * 32 + quad * 8];
        }
#pragma unroll
        for (int nt = 0; nt < 4; ++nt) {
            int n = wn + nt * 16 + r;
            short8 bh = *(const short8*)&smem[8192 + n * 32 + quad * 8];
            short8 bl = *(const short8*)&smem[12288 + n * 32 + quad * 8];
#pragma unroll
            for (int mt = 0; mt < 4; ++mt) {
                acc[mt][nt] = __builtin_amdgcn_mfma_f32_16x16x32_bf16(ah[mt], bh, acc[mt][nt], 0, 0, 0);
                acc[mt][nt] = __builtin_amdgcn_mfma_f32_16x16x32_bf16(ah[mt], bl, acc[mt][nt], 0, 0, 0);
                acc[mt][nt] = __builtin_amdgcn_mfma_f32_16x16x32_bf16(al[mt], bh, acc[mt][nt], 0, 0, 0);
            }
        }
        __syncthreads();
    }

    // ---- epilogue: bias+relu, per-wave LDS transpose (4 KB region), float4 stores
    float* eps = (float*)&smem[0] + wave * 1024;
    float bv[4];
#pragma unroll
    for (int nt = 0; nt < 4; ++nt) bv[nt] = bias[bn + wn + nt * 16 + r];
#pragma unroll
    for (int mt = 0; mt < 4; ++mt) {
#pragma unroll
        for (int nt = 0; nt < 4; ++nt)
#pragma unroll
            for (int reg = 0; reg < 4; ++reg)
                eps[(quad * 4 + reg) * 64 + nt * 16 + r] =
                    fmaxf(acc[mt][nt][reg] + bv[nt], 0.f);
        // same-wave LDS write->read: compiler inserts lgkmcnt wait
#pragma unroll
        for (int i = 0; i < 4; ++i) {
            int fl = i * 64 + lane;
            int ri = fl >> 4, c4 = fl & 15;
            float4 v = *(const float4*)&eps[ri * 64 + c4 * 4];
            int gm = bm + wm + mt * 16 + ri;
            if (gm < M) *(float4*)&C[(size_t)gm * Fout + bn + wn + c4 * 4] = v;
        }
    }
}

// ---------------- fp32 tiled GEMM (layer 1 only, K=8) ----------------

template <int BK>
__global__ __launch_bounds__(256) void k_gemm_bias_relu(
    const float* __restrict__ A, const float* __restrict__ W,
    const float* __restrict__ bias, float* __restrict__ C,
    int M, int K, int Fout) {
    const int BM = 128, BN = 128;
    __shared__ float As[BK][BM + 4];
    __shared__ float Bs[BK][BN];

    int bm = blockIdx.x * BM;
    int bn = blockIdx.y * BN;
    int tid = threadIdx.x;
    int tx = tid & 15;
    int ty = tid >> 4;

    float acc[8][8];
#pragma unroll
    for (int i = 0; i < 8; ++i)
#pragma unroll
        for (int j = 0; j < 8; ++j) acc[i][j] = 0.f;

    for (int k0 = 0; k0 < K; k0 += BK) {
#pragma unroll
        for (int i = tid; i < BM * BK; i += 256) {
            int k = i % BK;
            int m = i / BK;
            int gm = bm + m;
            As[k][m] = (gm < M) ? A[(long long)gm * K + k0 + k] : 0.f;
        }
#pragma unroll
        for (int i = tid; i < BK * BN; i += 256) {
            int n = i % BN;
            int k = i / BN;
            Bs[k][n] = W[(long long)(k0 + k) * Fout + bn + n];
        }
        __syncthreads();

#pragma unroll
        for (int k = 0; k < BK; ++k) {
            float a[8], b[8];
            float4 a0 = *(const float4*)&As[k][ty * 4];
            float4 a1 = *(const float4*)&As[k][ty * 4 + 64];
            float4 b0 = *(const float4*)&Bs[k][tx * 4];
            float4 b1 = *(const float4*)&Bs[k][tx * 4 + 64];
            a[0] = a0.x; a[1] = a0.y; a[2] = a0.z; a[3] = a0.w;
            a[4] = a1.x; a[5] = a1.y; a[6] = a1.z; a[7] = a1.w;
            b[0] = b0.x; b[1] = b0.y; b[2] = b0.z; b[3] = b0.w;
            b[4] = b1.x; b[5] = b1.y; b[6] = b1.z; b[7] = b1.w;
#pragma unroll
            for (int i = 0; i < 8; ++i)
#pragma unroll
                for (int j = 0; j < 8; ++j) acc[i][j] += a[i] * b[j];
        }
        __syncthreads();
    }

    float4 bi0 = *(const float4*)&bias[bn + tx * 4];
    float4 bi1 = *(const float4*)&bias[bn + tx * 4 + 64];
    float bb[8] = {bi0.x, bi0.y, bi0.z, bi0.w, bi1.x, bi1.y, bi1.z, bi1.w};
#pragma unroll
    for (int i = 0; i < 8; ++i) {
        int gm = bm + ((i < 4) ? (ty * 4 + i) : (64 + ty * 4 + i - 4));
        if (gm >= M) continue;
        float4 v0, v1;
        float* v0p = &v0.x;
        float* v1p = &v1.x;
#pragma unroll
        for (int j = 0; j < 4; ++j) {
            v0p[j] = fmaxf(acc[i][j] + bb[j], 0.f);
            v1p[j] = fmaxf(acc[i][j + 4] + bb[j + 4], 0.f);
        }
        *(float4*)&C[(long long)gm * Fout + bn + tx * 4] = v0;
        *(float4*)&C[(long long)gm * Fout + bn + tx * 4 + 64] = v1;
    }
}

// ---------------- pool stage 1: t[n] = h3[n,:512] . Wfc ----------------

__global__ __launch_bounds__(256) void k_dot(const float* __restrict__ h3,
                                             const float* __restrict__ Wfc,
                                             float* __restrict__ t, int N) {
    int wid = (int)((blockIdx.x * blockDim.x + threadIdx.x) >> 6);
    int lane = threadIdx.x & 63;
    if (wid >= N) return;
    const float* row = &h3[(size_t)wid * 512];
    float4 a0 = *(const float4*)&row[lane * 4];
    float4 a1 = *(const float4*)&row[lane * 4 + 256];
    float4 w0 = *(const float4*)&Wfc[lane * 4];
    float4 w1 = *(const float4*)&Wfc[lane * 4 + 256];
    float s = a0.x * w0.x + a0.y * w0.y + a0.z * w0.z + a0.w * w0.w
            + a1.x * w1.x + a1.y * w1.y + a1.z * w1.z + a1.w * w1.w;
#pragma unroll
    for (int off = 32; off > 0; off >>= 1) s += __shfl_down(s, off);
    if (lane == 0) t[wid] = s;
}

// ---------------- pool stage 2: segment mean + sigmoid ----------------

__global__ __launch_bounds__(256) void k_pool2(const float* __restrict__ t,
                                               const int* __restrict__ batch,
                                               const float* __restrict__ bfc,
                                               float* __restrict__ out, int N, int G) {
    int g = (int)((blockIdx.x * blockDim.x + threadIdx.x) >> 6);
    int lane = threadIdx.x & 63;
    if (g >= G) return;
    int lo = 0, hi = N;
    while (lo < hi) { int m = (lo + hi) >> 1; if (batch[m] < g) lo = m + 1; else hi = m; }
    int start = lo;
    hi = N;
    while (lo < hi) { int m = (lo + hi) >> 1; if (batch[m] < g + 1) lo = m + 1; else hi = m; }
    int end = lo;
    float s = 0.f;
    for (int i = start + lane; i < end; i += 64) s += t[i];
#pragma unroll
    for (int off = 32; off > 0; off >>= 1) s += __shfl_down(s, off);
    if (lane == 0) {
        float c = (float)(end - start);
        if (c < 1.f) c = 1.f;
        float z = s / c + bfc[0];
        out[g] = 1.f / (1.f + expf(-z));
    }
}

// ---------------- launcher ----------------

static inline int cdiv(int a, int b) { return (a + b - 1) / b; }

extern "C" void kernel_launch(void* const* d_in, const int* in_sizes, int n_in,
                              void* d_out, int out_size, void* d_ws, size_t ws_size,
                              hipStream_t stream) {
    const float* x   = (const float*)d_in[0];
    const int*   ei  = (const int*)d_in[1];
    const float* ew  = (const float*)d_in[2];
    const int*   bat = (const int*)d_in[3];
    const float* W1  = (const float*)d_in[4];
    const float* b1  = (const float*)d_in[5];
    const float* W2  = (const float*)d_in[6];
    const float* b2  = (const float*)d_in[7];
    const float* W3  = (const float*)d_in[8];
    const float* b3  = (const float*)d_in[9];
    const float* Wfc = (const float*)d_in[10];
    const float* bfc = (const float*)d_in[11];
    float* out = (float*)d_out;

    const int N  = in_sizes[3];
    const int E  = in_sizes[2];
    const int H0 = in_sizes[0] / N;   // 8
    const int H1 = in_sizes[5];       // 128
    const int H2 = in_sizes[7];       // 256
    const int H3 = in_sizes[9];       // 512
    const int G  = out_size;          // 256
    const int Mpad = cdiv(N, 128) * 128;
    const int Npad4 = (N + 4) & ~3;

    const int* srcv = ei;
    const int* dstv = ei + E;

    char* p = (char*)d_ws;
    float* dinv      = (float*)p; p += (size_t)N * 4;
    float* nrm       = (float*)p; p += (size_t)E * 4;
    int*   cnt       = (int*)p;   p += (size_t)N * 4;
    int*   cursor    = (int*)p;   p += (size_t)N * 4;
    int*   bsum      = (int*)p;   p += 256 * 4;
    int*   row_start = (int*)p;   p += (size_t)Npad4 * 4;
    int*   esrc      = (int*)p;   p += (size_t)E * 4;
    float* enorm     = (float*)p; p += (size_t)E * 4;
    float* tbuf      = (float*)p; p += (size_t)N * 4;
    unsigned short* WT2hi = (unsigned short*)p; p += (size_t)H1 * H2 * 2;
    unsigned short* WT2lo = (unsigned short*)p; p += (size_t)H1 * H2 * 2;
    unsigned short* WT3hi = (unsigned short*)p; p += (size_t)H2 * H3 * 2;
    unsigned short* WT3lo = (unsigned short*)p; p += (size_t)H2 * H3 * 2;
    unsigned short* Abhi  = (unsigned short*)p; p += (size_t)Mpad * H2 * 2;  // split-A, max K=256
    unsigned short* Ablo  = (unsigned short*)p; p += (size_t)Mpad * H2 * 2;
    float* big = (float*)p;  // Mpad*512 floats: h1 / h2 / h3 (sequentially dead), aggP overlay
    float* aggP = big + (size_t)Mpad * H2;  // layer-1 agg out (N*8), dead before h3 spans it

    // ---- precompute: deg/cnt -> dinv -> norm; CSR build
    k_init<<<cdiv(N, 256), 256, 0, stream>>>(dinv, cnt, cursor, N);
    k_hist_deg<<<cdiv(E, 256), 256, 0, stream>>>(dstv, ew, dinv, cnt, E);
    k_dinv<<<cdiv(N, 256), 256, 0, stream>>>(dinv, N);
    k_norm<<<cdiv(E, 256), 256, 0, stream>>>(srcv, dstv, ew, dinv, nrm, E);

    int nb = cdiv(N, 1024);
    k_scan_a<<<nb, 256, 0, stream>>>(cnt, bsum, N);
    k_scan_b<<<1, 256, 0, stream>>>(bsum, nb);
    k_scan_c<<<nb, 256, 0, stream>>>(cnt, bsum, row_start, N);
    k_scatter<<<cdiv(E, 256), 256, 0, stream>>>(srcv, dstv, nrm, row_start, cursor, esrc, enorm, E);

    // weight pre-split (tiny)
    k_wt_split<<<cdiv(H1 * H2, 256), 256, 0, stream>>>(W2, WT2hi, WT2lo, H1, H2);
    k_wt_split<<<cdiv(H2 * H3, 256), 256, 0, stream>>>(W3, WT3hi, WT3lo, H2, H3);

    // ---- layer 1: agg(x)[N,8] -> relu(@W1+b1)[N,128] = h1 in big  (fp32, K=8)
    {
        int sh = __builtin_ctz(H0);
        k_agg_f32<<<cdiv(N << sh, 256), 256, 0, stream>>>(x, dinv, esrc, enorm, row_start,
                                                          aggP, N, sh, H0 - 1);
        dim3 grid(cdiv(N, 128), H1 / 128);
        k_gemm_bias_relu<8><<<grid, 256, 0, stream>>>(aggP, W1, b1, big, N, H0, H1);
    }
    // ---- layer 2: agg(h1) -> split bf16 -> MFMA GEMM -> h2 in big
    {
        k_agg_bf<<<cdiv(Mpad * (H1 / 2), 256), 256, 0, stream>>>(
            big, dinv, esrc, enorm, row_start, Abhi, Ablo, N, Mpad, H1, __builtin_ctz(H1) - 1);
        dim3 grid(Mpad / 128, H2 / 128);
        k_gemm_async<<<grid, 256, 0, stream>>>(Abhi, Ablo, WT2hi, WT2lo, b2, big, N, H1, H2);
    }
    // ---- layer 3: agg(h2) -> split bf16 -> MFMA GEMM -> h3 in big
    {
        k_agg_bf<<<cdiv(Mpad * (H2 / 2), 256), 256, 0, stream>>>(
            big, dinv, esrc, enorm, row_start, Abhi, Ablo, N, Mpad, H2, __builtin_ctz(H2) - 1);
        dim3 grid(Mpad / 128, H3 / 128);
        k_gemm_async<<<grid, 256, 0, stream>>>(Abhi, Ablo, WT3hi, WT3lo, b3, big, N, H2, H3);
    }

    // ---- pool: per-row dot, then segment mean + sigmoid
    k_dot<<<cdiv(N * 64, 256), 256, 0, stream>>>(big, Wfc, tbuf, N);
    k_pool2<<<cdiv(G * 64, 256), 256, 0, stream>>>(tbuf, bat, bfc, out, N, G);
}

// Round 5
// 298.625 us; speedup vs baseline: 2.5549x; 1.1935x over previous
//
#include <hip/hip_runtime.h>
#include <math.h>

typedef __attribute__((ext_vector_type(8))) short short8;
typedef __attribute__((ext_vector_type(4))) float floatx4;

// ---------------- bf16 helpers ----------------

__device__ __forceinline__ unsigned short f2bf(float f) {
    unsigned int u = __float_as_uint(f);
    unsigned int r = (u + 0x7fffu + ((u >> 16) & 1u)) >> 16;  // RNE
    return (unsigned short)r;
}

// ---------------- precompute: deg/dinv/norm + dst histogram ----------------

__global__ void k_init(float* __restrict__ deg, int* __restrict__ cnt,
                       int* __restrict__ cursor, int N) {
    int i = blockIdx.x * blockDim.x + threadIdx.x;
    if (i < N) { deg[i] = 1.0f; cnt[i] = 0; cursor[i] = 0; }
}

__global__ void k_hist_deg(const int* __restrict__ dst, const float* __restrict__ ew,
                           float* __restrict__ deg, int* __restrict__ cnt, int E) {
    int e = blockIdx.x * blockDim.x + threadIdx.x;
    if (e < E) {
        int d = dst[e];
        atomicAdd(&deg[d], ew[e]);
        atomicAdd(&cnt[d], 1);
    }
}

__global__ void k_dinv(float* __restrict__ deg, int N) {
    int i = blockIdx.x * blockDim.x + threadIdx.x;
    if (i < N) deg[i] = rsqrtf(deg[i]);  // deg >= 1 (self-loop)
}

__global__ void k_norm(const int* __restrict__ src, const int* __restrict__ dst,
                       const float* __restrict__ ew, const float* __restrict__ dinv,
                       float* __restrict__ norm, int E) {
    int e = blockIdx.x * blockDim.x + threadIdx.x;
    if (e < E) norm[e] = dinv[src[e]] * ew[e] * dinv[dst[e]];
}

// ---------------- exclusive scan of cnt[N] -> row_start[N+1] ----------------

__global__ __launch_bounds__(256) void k_scan_a(const int* __restrict__ cnt,
                                                int* __restrict__ bsum, int N) {
    int b = blockIdx.x, t = threadIdx.x;
    int base = b * 1024 + t * 4;
    int s = 0;
#pragma unroll
    for (int j = 0; j < 4; ++j) { int i = base + j; if (i < N) s += cnt[i]; }
    __shared__ int sh[256];
    sh[t] = s; __syncthreads();
    for (int st = 128; st > 0; st >>= 1) { if (t < st) sh[t] += sh[t + st]; __syncthreads(); }
    if (t == 0) bsum[b] = sh[0];
}

__global__ __launch_bounds__(256) void k_scan_b(int* __restrict__ bsum, int nb) {
    int t = threadIdx.x;
    __shared__ int sh[256];
    int orig = (t < nb) ? bsum[t] : 0;
    sh[t] = orig; __syncthreads();
    for (int off = 1; off < 256; off <<= 1) {
        int x = (t >= off) ? sh[t - off] : 0;
        __syncthreads();
        sh[t] += x;
        __syncthreads();
    }
    if (t < nb) bsum[t] = sh[t] - orig;  // exclusive
}

__global__ __launch_bounds__(256) void k_scan_c(const int* __restrict__ cnt,
                                                const int* __restrict__ boff,
                                                int* __restrict__ row_start, int N) {
    int b = blockIdx.x, t = threadIdx.x;
    int base = b * 1024 + t * 4;
    int v[4]; int s = 0;
#pragma unroll
    for (int j = 0; j < 4; ++j) { int i = base + j; v[j] = (i < N) ? cnt[i] : 0; s += v[j]; }
    __shared__ int sh[256];
    sh[t] = s; __syncthreads();
    for (int off = 1; off < 256; off <<= 1) {
        int x = (t >= off) ? sh[t - off] : 0;
        __syncthreads();
        sh[t] += x;
        __syncthreads();
    }
    int excl = sh[t] - s + boff[b];
#pragma unroll
    for (int j = 0; j < 4; ++j) {
        int i = base + j;
        if (i < N) row_start[i] = excl;
        excl += v[j];
        if (i == N - 1) row_start[N] = excl;
    }
}

__global__ void k_scatter(const int* __restrict__ src, const int* __restrict__ dst,
                          const float* __restrict__ nrm, const int* __restrict__ row_start,
                          int* __restrict__ cursor, int* __restrict__ esrc,
                          float* __restrict__ enorm, int E) {
    int e = blockIdx.x * blockDim.x + threadIdx.x;
    if (e >= E) return;
    int d = dst[e];
    int pos = row_start[d] + atomicAdd(&cursor[d], 1);
    esrc[pos] = src[e];
    enorm[pos] = nrm[e];
}

// ---------------- aggregation, fp32 output (layer 1, F=8) ----------------

__global__ void k_agg_f32(const float* __restrict__ h, const float* __restrict__ dinv,
                          const int* __restrict__ esrc, const float* __restrict__ enorm,
                          const int* __restrict__ row_start, float* __restrict__ out,
                          int N, int shiftF, int maskF) {
    int gid = blockIdx.x * blockDim.x + threadIdx.x;
    if (gid >= (N << shiftF)) return;
    int n = gid >> shiftF;
    int f = gid & maskF;
    float dv = dinv[n];
    float acc = h[gid] * dv * dv;
    int s0 = row_start[n], s1 = row_start[n + 1];
    for (int j = s0; j < s1; ++j)
        acc += enorm[j] * h[((size_t)esrc[j] << shiftF) | f];
    out[gid] = acc;
}

// ---------------- aggregation, bf16 output (layers 2/3) ----------------
// Writes A [Mpad, F] bf16 (zeros for pad rows). 2 features/thread.

__global__ void k_agg_bf(const float* __restrict__ h, const float* __restrict__ dinv,
                         const int* __restrict__ esrc, const float* __restrict__ enorm,
                         const int* __restrict__ row_start,
                         unsigned short* __restrict__ A,
                         int N, int Mpad, int F, int hsh) {
    int p = blockIdx.x * blockDim.x + threadIdx.x;
    int half = F >> 1;
    if (p >= Mpad * half) return;
    int n = p >> hsh;                 // hsh = ctz(F) - 1
    int fp = (p & (half - 1)) << 1;
    size_t oidx = (size_t)n * F + fp;
    if (n >= N) {
        *(ushort2*)&A[oidx] = make_ushort2(0, 0);
        return;
    }
    float dv = dinv[n];
    float2 hv = *(const float2*)&h[oidx];
    float s0 = hv.x * dv * dv, s1 = hv.y * dv * dv;
    int j0 = row_start[n], j1 = row_start[n + 1];
    for (int j = j0; j < j1; ++j) {
        int s = esrc[j];
        float w = enorm[j];
        float2 nv = *(const float2*)&h[(size_t)s * F + fp];
        s0 += w * nv.x;
        s1 += w * nv.y;
    }
    *(ushort2*)&A[oidx] = make_ushort2(f2bf(s0), f2bf(s1));
}

// ---------------- weight transpose: W[K,Fout] fp32 -> WT[Fout,K] bf16 ----------------

__global__ void k_wt_bf(const float* __restrict__ W, unsigned short* __restrict__ WT,
                        int K, int Fout) {
    int gid = blockIdx.x * blockDim.x + threadIdx.x;
    if (gid >= K * Fout) return;
    int k = gid / Fout, n = gid % Fout;
    WT[(size_t)n * K + k] = f2bf(W[gid]);
}

// ---------------- bf16 MFMA GEMM with async LDS staging ----------------
// A [Mpad,K] bf16; WT [Fout,K] bf16. 128x128 tile, BK=32, 16 KB LDS,
// global_load_lds width-16. Grid: (Fout/128, Mpad/128) -- bn FAST so the
// 2..4 blocks sharing one A-tile run back-to-back and hit L2/L3.

__global__ __launch_bounds__(256, 4) void k_gemm_async(
    const unsigned short* __restrict__ A, const unsigned short* __restrict__ B,
    const float* __restrict__ bias, float* __restrict__ C,
    int M, int K, int Fout) {
    __shared__ __align__(16) unsigned short smem[8192];  // 16 KB: A tile + B tile

    int tid = threadIdx.x, wave = tid >> 6, lane = tid & 63;
    int quad = lane >> 4, r = lane & 15;
    int bn = blockIdx.x * 128, bm = blockIdx.y * 128;
    int wm = (wave & 1) * 64, wn = (wave >> 1) * 64;

    const unsigned short* gsrc[2] = {A, B};
    const int rb[2] = {bm, bn};

    floatx4 acc[4][4] = {};

    for (int k0 = 0; k0 < K; k0 += 32) {
        // stage 2 tiles (128 rows x 32 bf16 = 8 KB each), 2 chunks of 1 KB/wave/tile
#pragma unroll
        for (int t = 0; t < 2; ++t) {
#pragma unroll
            for (int i = 0; i < 2; ++i) {
                int q = wave * 2 + i;                 // wave-uniform chunk id
                int idx = q * 64 + lane;              // lane's 16B slot within tile
                int row = idx >> 2, kofs = (idx & 3) << 3;
                const unsigned short* g = gsrc[t] + ((size_t)(rb[t] + row) * K + k0 + kofs);
                unsigned short* l = &smem[t * 4096 + q * 512];  // wave-uniform base; HW adds lane*16
                __builtin_amdgcn_global_load_lds(
                    (const __attribute__((address_space(1))) void*)g,
                    (__attribute__((address_space(3))) void*)l, 16, 0, 0);
            }
        }
        __syncthreads();

        short8 ah[4];
#pragma unroll
        for (int mt = 0; mt < 4; ++mt) {
            int m = wm + mt * 16 + r;
            ah[mt] = *(const short8*)&smem[m * 32 + quad * 8];
        }
#pragma unroll
        for (int nt = 0; nt < 4; ++nt) {
            int n = wn + nt * 16 + r;
            short8 bh = *(const short8*)&smem[4096 + n * 32 + quad * 8];
#pragma unroll
            for (int mt = 0; mt < 4; ++mt)
                acc[mt][nt] = __builtin_amdgcn_mfma_f32_16x16x32_bf16(ah[mt], bh, acc[mt][nt], 0, 0, 0);
        }
        __syncthreads();
    }

    // ---- epilogue: bias+relu, per-wave LDS transpose (4 KB region), float4 stores
    float* eps = (float*)&smem[0] + wave * 1024;
    float bv[4];
#pragma unroll
    for (int nt = 0; nt < 4; ++nt) bv[nt] = bias[bn + wn + nt * 16 + r];
#pragma unroll
    for (int mt = 0; mt < 4; ++mt) {
#pragma unroll
        for (int nt = 0; nt < 4; ++nt)
#pragma unroll
            for (int reg = 0; reg < 4; ++reg)
                eps[(quad * 4 + reg) * 64 + nt * 16 + r] =
                    fmaxf(acc[mt][nt][reg] + bv[nt], 0.f);
#pragma unroll
        for (int i = 0; i < 4; ++i) {
            int fl = i * 64 + lane;
            int ri = fl >> 4, c4 = fl & 15;
            float4 v = *(const float4*)&eps[ri * 64 + c4 * 4];
            int gm = bm + wm + mt * 16 + ri;
            if (gm < M) *(float4*)&C[(size_t)gm * Fout + bn + wn + c4 * 4] = v;
        }
    }
}

// ---------------- fp32 tiled GEMM (layer 1 only, K=8) ----------------

template <int BK>
__global__ __launch_bounds__(256) void k_gemm_bias_relu(
    const float* __restrict__ A, const float* __restrict__ W,
    const float* __restrict__ bias, float* __restrict__ C,
    int M, int K, int Fout) {
    const int BM = 128, BN = 128;
    __shared__ float As[BK][BM + 4];
    __shared__ float Bs[BK][BN];

    int bm = blockIdx.x * BM;
    int bn = blockIdx.y * BN;
    int tid = threadIdx.x;
    int tx = tid & 15;
    int ty = tid >> 4;

    float acc[8][8];
#pragma unroll
    for (int i = 0; i < 8; ++i)
#pragma unroll
        for (int j = 0; j < 8; ++j) acc[i][j] = 0.f;

    for (int k0 = 0; k0 < K; k0 += BK) {
#pragma unroll
        for (int i = tid; i < BM * BK; i += 256) {
            int k = i % BK;
            int m = i / BK;
            int gm = bm + m;
            As[k][m] = (gm < M) ? A[(long long)gm * K + k0 + k] : 0.f;
        }
#pragma unroll
        for (int i = tid; i < BK * BN; i += 256) {
            int n = i % BN;
            int k = i / BN;
            Bs[k][n] = W[(long long)(k0 + k) * Fout + bn + n];
        }
        __syncthreads();

#pragma unroll
        for (int k = 0; k < BK; ++k) {
            float a[8], b[8];
            float4 a0 = *(const float4*)&As[k][ty * 4];
            float4 a1 = *(const float4*)&As[k][ty * 4 + 64];
            float4 b0 = *(const float4*)&Bs[k][tx * 4];
            float4 b1 = *(const float4*)&Bs[k][tx * 4 + 64];
            a[0] = a0.x; a[1] = a0.y; a[2] = a0.z; a[3] = a0.w;
            a[4] = a1.x; a[5] = a1.y; a[6] = a1.z; a[7] = a1.w;
            b[0] = b0.x; b[1] = b0.y; b[2] = b0.z; b[3] = b0.w;
            b[4] = b1.x; b[5] = b1.y; b[6] = b1.z; b[7] = b1.w;
#pragma unroll
            for (int i = 0; i < 8; ++i)
#pragma unroll
                for (int j = 0; j < 8; ++j) acc[i][j] += a[i] * b[j];
        }
        __syncthreads();
    }

    float4 bi0 = *(const float4*)&bias[bn + tx * 4];
    float4 bi1 = *(const float4*)&bias[bn + tx * 4 + 64];
    float bb[8] = {bi0.x, bi0.y, bi0.z, bi0.w, bi1.x, bi1.y, bi1.z, bi1.w};
#pragma unroll
    for (int i = 0; i < 8; ++i) {
        int gm = bm + ((i < 4) ? (ty * 4 + i) : (64 + ty * 4 + i - 4));
        if (gm >= M) continue;
        float4 v0, v1;
        float* v0p = &v0.x;
        float* v1p = &v1.x;
#pragma unroll
        for (int j = 0; j < 4; ++j) {
            v0p[j] = fmaxf(acc[i][j] + bb[j], 0.f);
            v1p[j] = fmaxf(acc[i][j + 4] + bb[j + 4], 0.f);
        }
        *(float4*)&C[(long long)gm * Fout + bn + tx * 4] = v0;
        *(float4*)&C[(long long)gm * Fout + bn + tx * 4 + 64] = v1;
    }
}

// ---------------- pool stage 1: t[n] = h3[n,:512] . Wfc ----------------

__global__ __launch_bounds__(256) void k_dot(const float* __restrict__ h3,
                                             const float* __restrict__ Wfc,
                                             float* __restrict__ t, int N) {
    int wid = (int)((blockIdx.x * blockDim.x + threadIdx.x) >> 6);
    int lane = threadIdx.x & 63;
    if (wid >= N) return;
    const float* row = &h3[(size_t)wid * 512];
    float4 a0 = *(const float4*)&row[lane * 4];
    float4 a1 = *(const float4*)&row[lane * 4 + 256];
    float4 w0 = *(const float4*)&Wfc[lane * 4];
    float4 w1 = *(const float4*)&Wfc[lane * 4 + 256];
    float s = a0.x * w0.x + a0.y * w0.y + a0.z * w0.z + a0.w * w0.w
            + a1.x * w1.x + a1.y * w1.y + a1.z * w1.z + a1.w * w1.w;
#pragma unroll
    for (int off = 32; off > 0; off >>= 1) s += __shfl_down(s, off);
    if (lane == 0) t[wid] = s;
}

// ---------------- pool stage 2: segment mean + sigmoid ----------------

__global__ __launch_bounds__(256) void k_pool2(const float* __restrict__ t,
                                               const int* __restrict__ batch,
                                               const float* __restrict__ bfc,
                                               float* __restrict__ out, int N, int G) {
    int g = (int)((blockIdx.x * blockDim.x + threadIdx.x) >> 6);
    int lane = threadIdx.x & 63;
    if (g >= G) return;
    int lo = 0, hi = N;
    while (lo < hi) { int m = (lo + hi) >> 1; if (batch[m] < g) lo = m + 1; else hi = m; }
    int start = lo;
    hi = N;
    while (lo < hi) { int m = (lo + hi) >> 1; if (batch[m] < g + 1) lo = m + 1; else hi = m; }
    int end = lo;
    float s = 0.f;
    for (int i = start + lane; i < end; i += 64) s += t[i];
#pragma unroll
    for (int off = 32; off > 0; off >>= 1) s += __shfl_down(s, off);
    if (lane == 0) {
        float c = (float)(end - start);
        if (c < 1.f) c = 1.f;
        float z = s / c + bfc[0];
        out[g] = 1.f / (1.f + expf(-z));
    }
}

// ---------------- launcher ----------------

static inline int cdiv(int a, int b) { return (a + b - 1) / b; }

extern "C" void kernel_launch(void* const* d_in, const int* in_sizes, int n_in,
                              void* d_out, int out_size, void* d_ws, size_t ws_size,
                              hipStream_t stream) {
    const float* x   = (const float*)d_in[0];
    const int*   ei  = (const int*)d_in[1];
    const float* ew  = (const float*)d_in[2];
    const int*   bat = (const int*)d_in[3];
    const float* W1  = (const float*)d_in[4];
    const float* b1  = (const float*)d_in[5];
    const float* W2  = (const float*)d_in[6];
    const float* b2  = (const float*)d_in[7];
    const float* W3  = (const float*)d_in[8];
    const float* b3  = (const float*)d_in[9];
    const float* Wfc = (const float*)d_in[10];
    const float* bfc = (const float*)d_in[11];
    float* out = (float*)d_out;

    const int N  = in_sizes[3];
    const int E  = in_sizes[2];
    const int H0 = in_sizes[0] / N;   // 8
    const int H1 = in_sizes[5];       // 128
    const int H2 = in_sizes[7];       // 256
    const int H3 = in_sizes[9];       // 512
    const int G  = out_size;          // 256
    const int Mpad = cdiv(N, 128) * 128;
    const int Npad4 = (N + 4) & ~3;

    const int* srcv = ei;
    const int* dstv = ei + E;

    char* p = (char*)d_ws;
    float* dinv      = (float*)p; p += (size_t)N * 4;
    float* nrm       = (float*)p; p += (size_t)E * 4;
    int*   cnt       = (int*)p;   p += (size_t)N * 4;
    int*   cursor    = (int*)p;   p += (size_t)N * 4;
    int*   bsum      = (int*)p;   p += 256 * 4;
    int*   row_start = (int*)p;   p += (size_t)Npad4 * 4;
    int*   esrc      = (int*)p;   p += (size_t)E * 4;
    float* enorm     = (float*)p; p += (size_t)E * 4;
    float* tbuf      = (float*)p; p += (size_t)N * 4;
    unsigned short* WT2 = (unsigned short*)p; p += (size_t)H1 * H2 * 2;
    unsigned short* WT3 = (unsigned short*)p; p += (size_t)H2 * H3 * 2;
    unsigned short* Abf = (unsigned short*)p; p += (size_t)Mpad * H2 * 2;  // bf16 A, max K=256
    float* big = (float*)p;  // Mpad*512 floats: h1 / h2 / h3 (sequentially dead), aggP overlay
    float* aggP = big + (size_t)Mpad * H2;  // layer-1 agg out (N*8), dead before h3 spans it

    // ---- precompute: deg/cnt -> dinv -> norm; CSR build
    k_init<<<cdiv(N, 256), 256, 0, stream>>>(dinv, cnt, cursor, N);
    k_hist_deg<<<cdiv(E, 256), 256, 0, stream>>>(dstv, ew, dinv, cnt, E);
    k_dinv<<<cdiv(N, 256), 256, 0, stream>>>(dinv, N);
    k_norm<<<cdiv(E, 256), 256, 0, stream>>>(srcv, dstv, ew, dinv, nrm, E);

    int nb = cdiv(N, 1024);
    k_scan_a<<<nb, 256, 0, stream>>>(cnt, bsum, N);
    k_scan_b<<<1, 256, 0, stream>>>(bsum, nb);
    k_scan_c<<<nb, 256, 0, stream>>>(cnt, bsum, row_start, N);
    k_scatter<<<cdiv(E, 256), 256, 0, stream>>>(srcv, dstv, nrm, row_start, cursor, esrc, enorm, E);

    // weight transpose->bf16 (tiny)
    k_wt_bf<<<cdiv(H1 * H2, 256), 256, 0, stream>>>(W2, WT2, H1, H2);
    k_wt_bf<<<cdiv(H2 * H3, 256), 256, 0, stream>>>(W3, WT3, H2, H3);

    // ---- layer 1: agg(x)[N,8] -> relu(@W1+b1)[N,128] = h1 in big  (fp32, K=8)
    {
        int sh = __builtin_ctz(H0);
        k_agg_f32<<<cdiv(N << sh, 256), 256, 0, stream>>>(x, dinv, esrc, enorm, row_start,
                                                          aggP, N, sh, H0 - 1);
        dim3 grid(cdiv(N, 128), H1 / 128);
        k_gemm_bias_relu<8><<<grid, 256, 0, stream>>>(aggP, W1, b1, big, N, H0, H1);
    }
    // ---- layer 2: agg(h1) -> bf16 -> MFMA GEMM -> h2 in big
    {
        k_agg_bf<<<cdiv(Mpad * (H1 / 2), 256), 256, 0, stream>>>(
            big, dinv, esrc, enorm, row_start, Abf, N, Mpad, H1, __builtin_ctz(H1) - 1);
        dim3 grid(H2 / 128, Mpad / 128);  // bn fast for A-tile L2/L3 reuse
        k_gemm_async<<<grid, 256, 0, stream>>>(Abf, WT2, b2, big, N, H1, H2);
    }
    // ---- layer 3: agg(h2) -> bf16 -> MFMA GEMM -> h3 in big
    {
        k_agg_bf<<<cdiv(Mpad * (H2 / 2), 256), 256, 0, stream>>>(
            big, dinv, esrc, enorm, row_start, Abf, N, Mpad, H2, __builtin_ctz(H2) - 1);
        dim3 grid(H3 / 128, Mpad / 128);  // bn fast
        k_gemm_async<<<grid, 256, 0, stream>>>(Abf, WT3, b3, big, N, H2, H3);
    }

    // ---- pool: per-row dot, then segment mean + sigmoid
    k_dot<<<cdiv(N * 64, 256), 256, 0, stream>>>(big, Wfc, tbuf, N);
    k_pool2<<<cdiv(G * 64, 256), 256, 0, stream>>>(tbuf, bat, bfc, out, N, G);
}

// Round 6
// 240.758 us; speedup vs baseline: 3.1690x; 1.2404x over previous
//
#include <hip/hip_runtime.h>
#include <math.h>

typedef __attribute__((ext_vector_type(8))) short short8;
typedef __attribute__((ext_vector_type(4))) float floatx4;

// ---------------- bf16 helpers ----------------

__device__ __forceinline__ unsigned short f2bf(float f) {
    unsigned int u = __float_as_uint(f);
    unsigned int r = (u + 0x7fffu + ((u >> 16) & 1u)) >> 16;  // RNE
    return (unsigned short)r;
}
__device__ __forceinline__ float bfu_lo(unsigned int u) {  // bf16 in bits[15:0]
    return __uint_as_float(u << 16);
}
__device__ __forceinline__ float bfu_hi(unsigned int u) {  // bf16 in bits[31:16]
    return __uint_as_float(u & 0xffff0000u);
}

// ---------------- precompute: deg/dinv/norm + dst histogram ----------------

__global__ void k_init(float* __restrict__ deg, int* __restrict__ cnt,
                       int* __restrict__ cursor, int N) {
    int i = blockIdx.x * blockDim.x + threadIdx.x;
    if (i < N) { deg[i] = 1.0f; cnt[i] = 0; cursor[i] = 0; }
}

__global__ void k_hist_deg(const int* __restrict__ dst, const float* __restrict__ ew,
                           float* __restrict__ deg, int* __restrict__ cnt, int E) {
    int e = blockIdx.x * blockDim.x + threadIdx.x;
    if (e < E) {
        int d = dst[e];
        atomicAdd(&deg[d], ew[e]);
        atomicAdd(&cnt[d], 1);
    }
}

__global__ void k_dinv(float* __restrict__ deg, int N) {
    int i = blockIdx.x * blockDim.x + threadIdx.x;
    if (i < N) deg[i] = rsqrtf(deg[i]);  // deg >= 1 (self-loop)
}

__global__ void k_norm(const int* __restrict__ src, const int* __restrict__ dst,
                       const float* __restrict__ ew, const float* __restrict__ dinv,
                       float* __restrict__ norm, int E) {
    int e = blockIdx.x * blockDim.x + threadIdx.x;
    if (e < E) norm[e] = dinv[src[e]] * ew[e] * dinv[dst[e]];
}

// ---------------- exclusive scan of cnt[N] -> row_start[N+1] ----------------

__global__ __launch_bounds__(256) void k_scan_a(const int* __restrict__ cnt,
                                                int* __restrict__ bsum, int N) {
    int b = blockIdx.x, t = threadIdx.x;
    int base = b * 1024 + t * 4;
    int s = 0;
#pragma unroll
    for (int j = 0; j < 4; ++j) { int i = base + j; if (i < N) s += cnt[i]; }
    __shared__ int sh[256];
    sh[t] = s; __syncthreads();
    for (int st = 128; st > 0; st >>= 1) { if (t < st) sh[t] += sh[t + st]; __syncthreads(); }
    if (t == 0) bsum[b] = sh[0];
}

__global__ __launch_bounds__(256) void k_scan_b(int* __restrict__ bsum, int nb) {
    int t = threadIdx.x;
    __shared__ int sh[256];
    int orig = (t < nb) ? bsum[t] : 0;
    sh[t] = orig; __syncthreads();
    for (int off = 1; off < 256; off <<= 1) {
        int x = (t >= off) ? sh[t - off] : 0;
        __syncthreads();
        sh[t] += x;
        __syncthreads();
    }
    if (t < nb) bsum[t] = sh[t] - orig;  // exclusive
}

__global__ __launch_bounds__(256) void k_scan_c(const int* __restrict__ cnt,
                                                const int* __restrict__ boff,
                                                int* __restrict__ row_start, int N) {
    int b = blockIdx.x, t = threadIdx.x;
    int base = b * 1024 + t * 4;
    int v[4]; int s = 0;
#pragma unroll
    for (int j = 0; j < 4; ++j) { int i = base + j; v[j] = (i < N) ? cnt[i] : 0; s += v[j]; }
    __shared__ int sh[256];
    sh[t] = s; __syncthreads();
    for (int off = 1; off < 256; off <<= 1) {
        int x = (t >= off) ? sh[t - off] : 0;
        __syncthreads();
        sh[t] += x;
        __syncthreads();
    }
    int excl = sh[t] - s + boff[b];
#pragma unroll
    for (int j = 0; j < 4; ++j) {
        int i = base + j;
        if (i < N) row_start[i] = excl;
        excl += v[j];
        if (i == N - 1) row_start[N] = excl;
    }
}

__global__ void k_scatter(const int* __restrict__ src, const int* __restrict__ dst,
                          const float* __restrict__ nrm, const int* __restrict__ row_start,
                          int* __restrict__ cursor, int* __restrict__ esrc,
                          float* __restrict__ enorm, int E) {
    int e = blockIdx.x * blockDim.x + threadIdx.x;
    if (e >= E) return;
    int d = dst[e];
    int pos = row_start[d] + atomicAdd(&cursor[d], 1);
    esrc[pos] = src[e];
    enorm[pos] = nrm[e];
}

// ---------------- aggregation, fp32 in/out (layer 1, F=8) ----------------

__global__ void k_agg_f32(const float* __restrict__ h, const float* __restrict__ dinv,
                          const int* __restrict__ esrc, const float* __restrict__ enorm,
                          const int* __restrict__ row_start, float* __restrict__ out,
                          int N, int shiftF, int maskF) {
    int gid = blockIdx.x * blockDim.x + threadIdx.x;
    if (gid >= (N << shiftF)) return;
    int n = gid >> shiftF;
    int f = gid & maskF;
    float dv = dinv[n];
    float acc = h[gid] * dv * dv;
    int s0 = row_start[n], s1 = row_start[n + 1];
    for (int j = s0; j < s1; ++j)
        acc += enorm[j] * h[((size_t)esrc[j] << shiftF) | f];
    out[gid] = acc;
}

// ---------------- aggregation, bf16 in -> bf16 out (layers 2/3) ----------------
// Reads h [N,F] bf16; writes A [Mpad,F] bf16 (zeros for pad rows). 4 feats/thread.

__global__ void k_agg_bf(const unsigned short* __restrict__ h, const float* __restrict__ dinv,
                         const int* __restrict__ esrc, const float* __restrict__ enorm,
                         const int* __restrict__ row_start,
                         unsigned short* __restrict__ A,
                         int N, int Mpad, int F, int qsh) {  // qsh = ctz(F) - 2
    int p = blockIdx.x * blockDim.x + threadIdx.x;
    int quart = F >> 2;
    if (p >= Mpad * quart) return;
    int n = p >> qsh;
    int fq = (p & (quart - 1)) << 2;
    size_t oidx = (size_t)n * F + fq;
    if (n >= N) {
        *(ushort4*)&A[oidx] = make_ushort4(0, 0, 0, 0);
        return;
    }
    float dv = dinv[n];
    float dv2 = dv * dv;
    uint2 hv = *(const uint2*)&h[oidx];
    float s0 = bfu_lo(hv.x) * dv2, s1 = bfu_hi(hv.x) * dv2;
    float s2 = bfu_lo(hv.y) * dv2, s3 = bfu_hi(hv.y) * dv2;
    int j0 = row_start[n], j1 = row_start[n + 1];
    for (int j = j0; j < j1; ++j) {
        int s = esrc[j];
        float w = enorm[j];
        uint2 nv = *(const uint2*)&h[(size_t)s * F + fq];
        s0 += w * bfu_lo(nv.x);
        s1 += w * bfu_hi(nv.x);
        s2 += w * bfu_lo(nv.y);
        s3 += w * bfu_hi(nv.y);
    }
    *(ushort4*)&A[oidx] = make_ushort4(f2bf(s0), f2bf(s1), f2bf(s2), f2bf(s3));
}

// ---------------- weight transpose: W[K,Fout] fp32 -> WT[Fout,K] bf16 ----------------

__global__ void k_wt_bf(const float* __restrict__ W, unsigned short* __restrict__ WT,
                        int K, int Fout) {
    int gid = blockIdx.x * blockDim.x + threadIdx.x;
    if (gid >= K * Fout) return;
    int k = gid / Fout, n = gid % Fout;
    WT[(size_t)n * K + k] = f2bf(W[gid]);
}

// ---------------- bf16 MFMA GEMM, async LDS staging, XCD-aware swizzle ----------------
// A [Mpad,K] bf16; WT [Fout,K] bf16. 128x128 tile, BK=32, 16 KB LDS.
// Linear grid (Mpad/128)*(Fout/128); Mpad/128 % 8 == 0. Swizzle: all bn-blocks of
// one bm-group land on the same XCD (P%8 const) for A-tile L2 reuse.
// EPI=0: C = relu(A@W+bias) stored bf16 [M,Fout].
// EPI=1: fused FC -- part[bnIdx*Mpad+row] = sum_n relu(..)*Wfc[n] (C unused).

template <int EPI>
__global__ __launch_bounds__(256, 4) void k_gemm_async(
    const unsigned short* __restrict__ A, const unsigned short* __restrict__ B,
    const float* __restrict__ bias, unsigned short* __restrict__ C,
    const float* __restrict__ Wfc, float* __restrict__ part,
    int M, int Mpad, int K, int Fout, int nbsh) {
    __shared__ __align__(16) unsigned short smem[8192];  // 16 KB

    int tid = threadIdx.x, wave = tid >> 6, lane = tid & 63;
    int quad = lane >> 4, r = lane & 15;

    // XCD swizzle: P = g%8 + 8*(bnIdx + NB*(g/8))
    int P = blockIdx.x;
    int r8 = P & 7;
    int q = P >> 3;
    int bnIdx = q & ((1 << nbsh) - 1);
    int g = ((q >> nbsh) << 3) + r8;
    int bm = g * 128, bn = bnIdx * 128;
    int wm = (wave & 1) * 64, wn = (wave >> 1) * 64;

    const unsigned short* gsrc[2] = {A, B};
    const int rb[2] = {bm, bn};

    floatx4 acc[4][4] = {};

    for (int k0 = 0; k0 < K; k0 += 32) {
#pragma unroll
        for (int t = 0; t < 2; ++t) {
#pragma unroll
            for (int i = 0; i < 2; ++i) {
                int qc = wave * 2 + i;                // wave-uniform chunk id
                int idx = qc * 64 + lane;             // lane's 16B slot within tile
                int row = idx >> 2, kofs = (idx & 3) << 3;
                const unsigned short* gptr = gsrc[t] + ((size_t)(rb[t] + row) * K + k0 + kofs);
                unsigned short* l = &smem[t * 4096 + qc * 512];  // wave-uniform base
                __builtin_amdgcn_global_load_lds(
                    (const __attribute__((address_space(1))) void*)gptr,
                    (__attribute__((address_space(3))) void*)l, 16, 0, 0);
            }
        }
        __syncthreads();

        short8 ah[4];
#pragma unroll
        for (int mt = 0; mt < 4; ++mt) {
            int m = wm + mt * 16 + r;
            ah[mt] = *(const short8*)&smem[m * 32 + quad * 8];
        }
#pragma unroll
        for (int nt = 0; nt < 4; ++nt) {
            int n = wn + nt * 16 + r;
            short8 bh = *(const short8*)&smem[4096 + n * 32 + quad * 8];
#pragma unroll
            for (int mt = 0; mt < 4; ++mt)
                acc[mt][nt] = __builtin_amdgcn_mfma_f32_16x16x32_bf16(ah[mt], bh, acc[mt][nt], 0, 0, 0);
        }
        __syncthreads();
    }

    float bv[4];
#pragma unroll
    for (int nt = 0; nt < 4; ++nt) bv[nt] = bias[bn + wn + nt * 16 + r];

    if (EPI == 0) {
        // bf16 C store via per-wave LDS transpose (4 KB region)
        float* eps = (float*)&smem[0] + wave * 1024;
#pragma unroll
        for (int mt = 0; mt < 4; ++mt) {
#pragma unroll
            for (int nt = 0; nt < 4; ++nt)
#pragma unroll
                for (int reg = 0; reg < 4; ++reg)
                    eps[(quad * 4 + reg) * 64 + nt * 16 + r] =
                        fmaxf(acc[mt][nt][reg] + bv[nt], 0.f);
#pragma unroll
            for (int i = 0; i < 4; ++i) {
                int fl = i * 64 + lane;
                int ri = fl >> 4, c4 = fl & 15;
                float4 v = *(const float4*)&eps[ri * 64 + c4 * 4];
                int gm = bm + wm + mt * 16 + ri;
                if (gm < M)
                    *(ushort4*)&C[(size_t)gm * Fout + bn + wn + c4 * 4] =
                        make_ushort4(f2bf(v.x), f2bf(v.y), f2bf(v.z), f2bf(v.w));
            }
        }
    } else {
        // fused FC dot: rowsum[128] over the block's 128 columns
        float* rowsum = (float*)&smem[0];
        if (tid < 128) rowsum[tid] = 0.f;
        __syncthreads();
        float wf[4];
#pragma unroll
        for (int nt = 0; nt < 4; ++nt) wf[nt] = Wfc[bn + wn + nt * 16 + r];
#pragma unroll
        for (int mt = 0; mt < 4; ++mt)
#pragma unroll
            for (int reg = 0; reg < 4; ++reg) {
                float v = 0.f;
#pragma unroll
                for (int nt = 0; nt < 4; ++nt)
                    v += fmaxf(acc[mt][nt][reg] + bv[nt], 0.f) * wf[nt];
                v += __shfl_xor(v, 1);
                v += __shfl_xor(v, 2);
                v += __shfl_xor(v, 4);
                v += __shfl_xor(v, 8);
                if (r == 0) atomicAdd(&rowsum[wm + mt * 16 + quad * 4 + reg], v);
            }
        __syncthreads();
        if (tid < 128) part[(size_t)bnIdx * Mpad + bm + tid] = rowsum[tid];
    }
}

// ---------------- fp32 tiled GEMM, bf16 out (layer 1, K=8) ----------------

template <int BK>
__global__ __launch_bounds__(256) void k_gemm_bias_relu(
    const float* __restrict__ A, const float* __restrict__ W,
    const float* __restrict__ bias, unsigned short* __restrict__ C,
    int M, int K, int Fout) {
    const int BM = 128, BN = 128;
    __shared__ float As[BK][BM + 4];
    __shared__ float Bs[BK][BN];

    int bm = blockIdx.x * BM;
    int bn = blockIdx.y * BN;
    int tid = threadIdx.x;
    int tx = tid & 15;
    int ty = tid >> 4;

    float acc[8][8];
#pragma unroll
    for (int i = 0; i < 8; ++i)
#pragma unroll
        for (int j = 0; j < 8; ++j) acc[i][j] = 0.f;

    for (int k0 = 0; k0 < K; k0 += BK) {
#pragma unroll
        for (int i = tid; i < BM * BK; i += 256) {
            int k = i % BK;
            int m = i / BK;
            int gm = bm + m;
            As[k][m] = (gm < M) ? A[(long long)gm * K + k0 + k] : 0.f;
        }
#pragma unroll
        for (int i = tid; i < BK * BN; i += 256) {
            int n = i % BN;
            int k = i / BN;
            Bs[k][n] = W[(long long)(k0 + k) * Fout + bn + n];
        }
        __syncthreads();

#pragma unroll
        for (int k = 0; k < BK; ++k) {
            float a[8], b[8];
            float4 a0 = *(const float4*)&As[k][ty * 4];
            float4 a1 = *(const float4*)&As[k][ty * 4 + 64];
            float4 b0 = *(const float4*)&Bs[k][tx * 4];
            float4 b1 = *(const float4*)&Bs[k][tx * 4 + 64];
            a[0] = a0.x; a[1] = a0.y; a[2] = a0.z; a[3] = a0.w;
            a[4] = a1.x; a[5] = a1.y; a[6] = a1.z; a[7] = a1.w;
            b[0] = b0.x; b[1] = b0.y; b[2] = b0.z; b[3] = b0.w;
            b[4] = b1.x; b[5] = b1.y; b[6] = b1.z; b[7] = b1.w;
#pragma unroll
            for (int i = 0; i < 8; ++i)
#pragma unroll
                for (int j = 0; j < 8; ++j) acc[i][j] += a[i] * b[j];
        }
        __syncthreads();
    }

    float4 bi0 = *(const float4*)&bias[bn + tx * 4];
    float4 bi1 = *(const float4*)&bias[bn + tx * 4 + 64];
    float bb[8] = {bi0.x, bi0.y, bi0.z, bi0.w, bi1.x, bi1.y, bi1.z, bi1.w};
#pragma unroll
    for (int i = 0; i < 8; ++i) {
        int gm = bm + ((i < 4) ? (ty * 4 + i) : (64 + ty * 4 + i - 4));
        if (gm >= M) continue;
        ushort4 v0, v1;
        v0.x = f2bf(fmaxf(acc[i][0] + bb[0], 0.f));
        v0.y = f2bf(fmaxf(acc[i][1] + bb[1], 0.f));
        v0.z = f2bf(fmaxf(acc[i][2] + bb[2], 0.f));
        v0.w = f2bf(fmaxf(acc[i][3] + bb[3], 0.f));
        v1.x = f2bf(fmaxf(acc[i][4] + bb[4], 0.f));
        v1.y = f2bf(fmaxf(acc[i][5] + bb[5], 0.f));
        v1.z = f2bf(fmaxf(acc[i][6] + bb[6], 0.f));
        v1.w = f2bf(fmaxf(acc[i][7] + bb[7], 0.f));
        *(ushort4*)&C[(long long)gm * Fout + bn + tx * 4] = v0;
        *(ushort4*)&C[(long long)gm * Fout + bn + tx * 4 + 64] = v1;
    }
}

// ---------------- pool: t[n]=sum_c part[c][n]; segment mean + sigmoid ----------------

__global__ __launch_bounds__(256) void k_pool2(const float* __restrict__ part,
                                               const int* __restrict__ batch,
                                               const float* __restrict__ bfc,
                                               float* __restrict__ out,
                                               int N, int Mpad, int nchunks, int G) {
    int g = (int)((blockIdx.x * blockDim.x + threadIdx.x) >> 6);
    int lane = threadIdx.x & 63;
    if (g >= G) return;
    int lo = 0, hi = N;
    while (lo < hi) { int m = (lo + hi) >> 1; if (batch[m] < g) lo = m + 1; else hi = m; }
    int start = lo;
    hi = N;
    while (lo < hi) { int m = (lo + hi) >> 1; if (batch[m] < g + 1) lo = m + 1; else hi = m; }
    int end = lo;
    float s = 0.f;
    for (int i = start + lane; i < end; i += 64) {
        float t = 0.f;
        for (int c = 0; c < nchunks; ++c) t += part[(size_t)c * Mpad + i];
        s += t;
    }
#pragma unroll
    for (int off = 32; off > 0; off >>= 1) s += __shfl_down(s, off);
    if (lane == 0) {
        float c = (float)(end - start);
        if (c < 1.f) c = 1.f;
        float z = s / c + bfc[0];
        out[g] = 1.f / (1.f + expf(-z));
    }
}

// ---------------- launcher ----------------

static inline int cdiv(int a, int b) { return (a + b - 1) / b; }

extern "C" void kernel_launch(void* const* d_in, const int* in_sizes, int n_in,
                              void* d_out, int out_size, void* d_ws, size_t ws_size,
                              hipStream_t stream) {
    const float* x   = (const float*)d_in[0];
    const int*   ei  = (const int*)d_in[1];
    const float* ew  = (const float*)d_in[2];
    const int*   bat = (const int*)d_in[3];
    const float* W1  = (const float*)d_in[4];
    const float* b1  = (const float*)d_in[5];
    const float* W2  = (const float*)d_in[6];
    const float* b2  = (const float*)d_in[7];
    const float* W3  = (const float*)d_in[8];
    const float* b3  = (const float*)d_in[9];
    const float* Wfc = (const float*)d_in[10];
    const float* bfc = (const float*)d_in[11];
    float* out = (float*)d_out;

    const int N  = in_sizes[3];
    const int E  = in_sizes[2];
    const int H0 = in_sizes[0] / N;   // 8
    const int H1 = in_sizes[5];       // 128
    const int H2 = in_sizes[7];       // 256
    const int H3 = in_sizes[9];       // 512
    const int G  = out_size;          // 256
    const int Mpad = cdiv(N, 1024) * 1024;  // /128 divisible by 8 (XCD swizzle)
    const int Npad4 = (N + 4) & ~3;

    const int* srcv = ei;
    const int* dstv = ei + E;

    char* p = (char*)d_ws;
    float* dinv      = (float*)p; p += (size_t)N * 4;
    float* nrm       = (float*)p; p += (size_t)E * 4;
    int*   cnt       = (int*)p;   p += (size_t)N * 4;
    int*   cursor    = (int*)p;   p += (size_t)N * 4;
    int*   bsum      = (int*)p;   p += 256 * 4;
    int*   row_start = (int*)p;   p += (size_t)Npad4 * 4;
    int*   esrc      = (int*)p;   p += (size_t)E * 4;
    float* enorm     = (float*)p; p += (size_t)E * 4;
    float* part      = (float*)p; p += (size_t)(H3 / 128) * Mpad * 4;
    unsigned short* WT2 = (unsigned short*)p; p += (size_t)H1 * H2 * 2;
    unsigned short* WT3 = (unsigned short*)p; p += (size_t)H2 * H3 * 2;
    unsigned short* Abf = (unsigned short*)p; p += (size_t)Mpad * H2 * 2;  // bf16 A, max K=256
    unsigned short* h1  = (unsigned short*)p; p += (size_t)Mpad * H1 * 2;
    unsigned short* h2  = (unsigned short*)p; p += (size_t)Mpad * H2 * 2;
    float* aggP = (float*)p;      p += (size_t)N * H0 * 4;

    // ---- precompute: deg/cnt -> dinv -> norm; CSR build
    k_init<<<cdiv(N, 256), 256, 0, stream>>>(dinv, cnt, cursor, N);
    k_hist_deg<<<cdiv(E, 256), 256, 0, stream>>>(dstv, ew, dinv, cnt, E);
    k_dinv<<<cdiv(N, 256), 256, 0, stream>>>(dinv, N);
    k_norm<<<cdiv(E, 256), 256, 0, stream>>>(srcv, dstv, ew, dinv, nrm, E);

    int nb = cdiv(N, 1024);
    k_scan_a<<<nb, 256, 0, stream>>>(cnt, bsum, N);
    k_scan_b<<<1, 256, 0, stream>>>(bsum, nb);
    k_scan_c<<<nb, 256, 0, stream>>>(cnt, bsum, row_start, N);
    k_scatter<<<cdiv(E, 256), 256, 0, stream>>>(srcv, dstv, nrm, row_start, cursor, esrc, enorm, E);

    // weight transpose->bf16 (tiny)
    k_wt_bf<<<cdiv(H1 * H2, 256), 256, 0, stream>>>(W2, WT2, H1, H2);
    k_wt_bf<<<cdiv(H2 * H3, 256), 256, 0, stream>>>(W3, WT3, H2, H3);

    // ---- layer 1: agg(x)[N,8] fp32 -> relu(@W1+b1) -> h1 bf16 [N,128]
    {
        int sh = __builtin_ctz(H0);
        k_agg_f32<<<cdiv(N << sh, 256), 256, 0, stream>>>(x, dinv, esrc, enorm, row_start,
                                                          aggP, N, sh, H0 - 1);
        dim3 grid(cdiv(N, 128), H1 / 128);
        k_gemm_bias_relu<8><<<grid, 256, 0, stream>>>(aggP, W1, b1, h1, N, H0, H1);
    }
    // ---- layer 2: agg(h1 bf16) -> Abf -> MFMA GEMM -> h2 bf16 [N,256]
    {
        k_agg_bf<<<cdiv(Mpad * (H1 / 4), 256), 256, 0, stream>>>(
            h1, dinv, esrc, enorm, row_start, Abf, N, Mpad, H1, __builtin_ctz(H1) - 2);
        int nbsh = __builtin_ctz(H2 / 128);  // NB=2
        k_gemm_async<0><<<(Mpad / 128) * (H2 / 128), 256, 0, stream>>>(
            Abf, WT2, b2, h2, nullptr, nullptr, N, Mpad, H1, H2, nbsh);
    }
    // ---- layer 3: agg(h2 bf16) -> Abf -> MFMA GEMM + fused FC dot -> part[4][Mpad]
    {
        k_agg_bf<<<cdiv(Mpad * (H2 / 4), 256), 256, 0, stream>>>(
            h2, dinv, esrc, enorm, row_start, Abf, N, Mpad, H2, __builtin_ctz(H2) - 2);
        int nbsh = __builtin_ctz(H3 / 128);  // NB=4
        k_gemm_async<1><<<(Mpad / 128) * (H3 / 128), 256, 0, stream>>>(
            Abf, WT3, b3, nullptr, Wfc, part, N, Mpad, H2, H3, nbsh);
    }

    // ---- pool: segment mean of summed partials + sigmoid
    k_pool2<<<cdiv(G * 64, 256), 256, 0, stream>>>(part, bat, bfc, out, N, Mpad, H3 / 128, G);
}